// Round 5
// baseline (410.469 us; speedup 1.0000x reference)
//
#include <hip/hip_runtime.h>
#include <cstdint>
#include <cstddef>

// ============================================================================
// MildAugmentStage: random-resized-crop (cubic, antialias) + color jitter +
// separable gaussian blur, reproducing jax.random (threefry2x32) exactly.
// Round 4: y-pass as dense per-(b,tile) 16x24 SGPR matrix (zero LDS in y),
// 112-B-stride col-major staging (natural bank spread), 28 KB LDS.
// ============================================================================

#define JAX_PARTITIONABLE 1

#define NB 256
#define NC 3
#define IH 256
#define IW 256
#define OS 224
#define PIX (OS * OS)         // 50176
#define PSTRIDE 32
#define TROWS 16              // output rows per resize/blur tile
#define LROWS 24              // max staged input rows
#define NTILE 14              // 224/16
#define CSTRIDE 28            // dwords per staged column (112 B)

// ---------------- bf16 helpers ----------------
__device__ __forceinline__ float bf2f(unsigned short u) {
  return __uint_as_float(((unsigned)u) << 16);
}
__device__ __forceinline__ unsigned short f2bf(float f) {
  unsigned u = __float_as_uint(f);
  return (unsigned short)((u + 0x7FFFu + ((u >> 16) & 1u)) >> 16);
}

// ---------------- threefry-2x32 ----------------
__device__ __forceinline__ void tf2x32(uint32_t k0, uint32_t k1,
                                       uint32_t x0, uint32_t x1,
                                       uint32_t& o0, uint32_t& o1) {
  uint32_t ks[3] = {k0, k1, k0 ^ k1 ^ 0x1BD11BDAu};
  uint32_t a = x0 + ks[0], b = x1 + ks[1];
  const int R[2][4] = {{13, 15, 26, 6}, {17, 29, 16, 24}};
  #pragma unroll
  for (int i = 0; i < 5; ++i) {
    #pragma unroll
    for (int j = 0; j < 4; ++j) {
      int r = R[i & 1][j];
      a += b;
      b = (b << r) | (b >> (32 - r));
      b ^= a;
    }
    a += ks[(i + 1) % 3];
    b += ks[(i + 2) % 3] + (uint32_t)(i + 1);
  }
  o0 = a; o1 = b;
}

__device__ __forceinline__ float bits_to_u01(uint32_t bits) {
  uint32_t fb = (bits >> 9) | 0x3f800000u;
  return __uint_as_float(fb) - 1.0f;
}

__device__ __forceinline__ float u01_n(uint32_t k0, uint32_t k1, uint32_t i, uint32_t N) {
#if JAX_PARTITIONABLE
  uint32_t a, b; tf2x32(k0, k1, 0u, i, a, b);
  return bits_to_u01(a ^ b);
#else
  uint32_t half = N >> 1;
  uint32_t a, b;
  if (i < half) { tf2x32(k0, k1, i, half + i, a, b); return bits_to_u01(a); }
  tf2x32(k0, k1, i - half, i, a, b); return bits_to_u01(b);
#endif
}

__device__ __forceinline__ float junif(uint32_t k0, uint32_t k1, uint32_t i, uint32_t N,
                                       float mn, float mx) {
  float u = u01_n(k0, k1, i, N);
  float d = __fsub_rn(mx, mn);
  float r = __fadd_rn(__fmul_rn(u, d), mn);
  return fmaxf(mn, r);
}

// ---------------- per-batch augmentation parameters ----------------
__global__ __launch_bounds__(256) void k_params(float* __restrict__ prm) {
  int b = threadIdx.x;
  if (b >= NB) return;
  uint32_t ks[10][2];
#if JAX_PARTITIONABLE
  for (int j = 0; j < 10; ++j) tf2x32(0u, 42u, 0u, (uint32_t)j, ks[j][0], ks[j][1]);
#else
  {
    uint32_t flat[20];
    for (int j = 0; j < 10; ++j) {
      uint32_t a, bb; tf2x32(0u, 42u, (uint32_t)j, (uint32_t)(10 + j), a, bb);
      flat[j] = a; flat[10 + j] = bb;
    }
    for (int j = 0; j < 10; ++j) { ks[j][0] = flat[2 * j]; ks[j][1] = flat[2 * j + 1]; }
  }
#endif
  float* P = prm + b * PSTRIDE;

  float uarea = junif(ks[0][0], ks[0][1], b, NB, 0.8f, 1.0f);
  float area  = __fmul_rn(65536.0f, uarea);
  float lmn = (float)(-0.28768207245178085);
  float lmx = (float)( 0.28768207245178085);
  float ur  = junif(ks[1][0], ks[1][1], b, NB, lmn, lmx);
  float ratio = (float)exp((double)ur);

  float cw = rintf(__fsqrt_rn(__fmul_rn(area, ratio)));
  cw = fminf(fmaxf(cw, 1.0f), 256.0f);
  float ch = rintf(__fsqrt_rn(__fdiv_rn(area, ratio)));
  ch = fminf(fmaxf(ch, 1.0f), 256.0f);

  float ui = u01_n(ks[2][0], ks[2][1], b, NB);
  float uj = u01_n(ks[3][0], ks[3][1], b, NB);
  float i0 = floorf(__fmul_rn(ui, __fadd_rn(__fsub_rn(256.0f, ch), 1.0f)));
  float j0 = floorf(__fmul_rn(uj, __fadd_rn(__fsub_rn(256.0f, cw), 1.0f)));

  float sy = __fdiv_rn(224.0f, ch), sx = __fdiv_rn(224.0f, cw);
  float ty = -__fmul_rn(i0, sy),   tx = -__fmul_rn(j0, sx);
  float inv_sy = __fdiv_rn(1.0f, sy), inv_sx = __fdiv_rn(1.0f, sx);
  P[0] = inv_sy;
  P[1] = __fmul_rn(ty, inv_sy);
  P[2] = fmaxf(inv_sy, 1.0f);
  P[3] = inv_sx;
  P[4] = __fmul_rn(tx, inv_sx);
  P[5] = fmaxf(inv_sx, 1.0f);

  P[6] = junif(ks[4][0], ks[4][1], b, NB, 0.9f, 1.1f);
  P[7] = junif(ks[5][0], ks[5][1], b, NB, 0.9f, 1.1f);
  P[8] = junif(ks[6][0], ks[6][1], b, NB, 0.9f, 1.1f);
  P[9] = junif(ks[7][0], ks[7][1], b, NB, -0.01f, 0.01f);
  P[10] = (u01_n(ks[8][0], ks[8][1], b, NB) < 0.8f) ? 1.0f : 0.0f;

  uint32_t kb0[2], kb1[2];
#if JAX_PARTITIONABLE
  tf2x32(ks[9][0], ks[9][1], 0u, 0u, kb0[0], kb0[1]);
  tf2x32(ks[9][0], ks[9][1], 0u, 1u, kb1[0], kb1[1]);
#else
  {
    uint32_t f0, s0, f1, s1;
    tf2x32(ks[9][0], ks[9][1], 0u, 2u, f0, s0);
    tf2x32(ks[9][0], ks[9][1], 1u, 3u, f1, s1);
    kb0[0] = f0; kb0[1] = f1; kb1[0] = s0; kb1[1] = s1;
  }
#endif
  float sg = junif(kb0[0], kb0[1], b, NB, 0.1f, 2.0f);
  P[11] = (u01_n(kb1[0], kb1[1], b, NB) < 0.5f) ? 1.0f : 0.0f;

  float e[15]; float ssum = 0.0f;
  for (int k = 0; k < 15; ++k) {
    float t = (float)k - 7.0f;
    float z = t / sg;
    e[k] = expf(-0.5f * (z * z));
    ssum += e[k];
  }
  for (int k = 0; k < 15; ++k) P[12 + k] = e[k] / ssum;
}

// ---------------- cubic (Keys, a=-0.5) ----------------
__device__ __forceinline__ float keys_cubic(float x) {
  float o = ((1.5f * x - 2.5f) * x) * x + 1.0f;
  if (x >= 1.0f) o = ((-0.5f * x + 2.5f) * x - 4.0f) * x + 2.0f;
  if (x >= 2.0f) o = 0.0f;
  return o;
}

// ---------------- per-batch resize weight tables ----------------
// wtab[b][dim(0=y,1=x)][o][8]: w0..w5, i0, ntaps
__global__ __launch_bounds__(224) void k_weights(const float* __restrict__ prm,
                                                 float* __restrict__ wtab) {
  int o = threadIdx.x;
  int dim = blockIdx.x & 1;
  int b = blockIdx.x >> 1;
  const float* P = prm + b * PSTRIDE;
  float inv = dim ? P[3] : P[0];
  float ti  = dim ? P[4] : P[1];
  float ks  = dim ? P[5] : P[2];
  float sf = ((float)o + 0.5f) * inv - ti - 0.5f;
  float r = 2.0f * ks;
  int i0 = max(0, (int)ceilf(sf - r));
  int i1 = min(255, (int)floorf(sf + r));
  int n = i1 - i0 + 1; if (n > 6) n = 6;
  float w[6]; float tot = 0.0f;
  #pragma unroll
  for (int j = 0; j < 6; ++j) {
    float v = 0.0f;
    if (j < n) { float d = fabsf(sf - (float)(i0 + j)) / ks; v = keys_cubic(d); }
    w[j] = v; tot += v;
  }
  float ri = (fabsf(tot) > 1.1920929e-4f) ? (1.0f / tot) : 0.0f;
  float* W = wtab + ((size_t)(b * 2 + dim) * 224 + o) * 8;
  #pragma unroll
  for (int j = 0; j < 6; ++j) W[j] = w[j] * ri;
  W[6] = (float)i0;
  W[7] = (float)n;
}

// ---------------- dense per-(b,tile) y-matrix: My[b][tile][16][24] ---------
__global__ __launch_bounds__(384) void k_ymat(const float* __restrict__ wtab,
                                              float* __restrict__ My) {
  int blk = blockIdx.x;                 // b*NTILE + tile
  int tile = blk % NTILE;
  int b = blk / NTILE;
  int e = threadIdx.x;                  // i*24 + r
  int i = e / 24, r = e - i * 24;
  const float* Wy = wtab + ((size_t)(b * 2) * 224 + tile * TROWS) * 8;
  int base = (int)Wy[6];                // iy0 of tile's first output row
  const float* Wrow = Wy + i * 8;
  int j = base + r - (int)Wrow[6];
  float m = 0.0f;
  #pragma unroll
  for (int jj = 0; jj < 6; ++jj) {
    if (jj == j) m = Wrow[jj];
  }
  My[(size_t)blk * 16 * 24 + e] = m;
}

// ---------------- tiled separable resize (x in LDS cols, y dense SGPR) ----
__global__ __launch_bounds__(256) void k_resize(const float* __restrict__ x,
                                                float* __restrict__ xc,
                                                float* __restrict__ rowsum,
                                                const float* __restrict__ prm,
                                                const float* __restrict__ wtab,
                                                const float* __restrict__ My) {
  int blk = blockIdx.x;
  int tile = blk % NTILE;
  int c = (blk / NTILE) % NC;
  int b = blk / (NTILE * NC);
  int t = threadIdx.x;
  int oyb = tile * TROWS;
  const float* P = prm + b * PSTRIDE;
  const float* wty = wtab + ((size_t)(b * 2) * 224 + oyb) * 8;   // uniform

  __shared__ __align__(16) float s_mem[256 * CSTRIDE];   // 28672 B col-major
  __shared__ float wsum[4];

  int base = (int)wty[6];
  int last = (int)wty[15 * 8 + 6];
  int rows = min(last + 6, IH) - base; if (rows > LROWS) rows = LROWS;
  int nchunk = (rows + 3) >> 2;                           // uniform, 5..6

  // stage column t: nchunk chunks of 4 rows, b128 writes at col*28 + 4k dwords
  {
    const float* src = x + (size_t)(b * NC + c) * IH * IW + t;
    float* colp = s_mem + t * CSTRIDE;
    #pragma unroll
    for (int k = 0; k < 6; ++k) {
      if (k < nchunk) {
        float4 v;
        v.x = src[(size_t)min(base + 4 * k + 0, IH - 1) * IW];
        v.y = src[(size_t)min(base + 4 * k + 1, IH - 1) * IW];
        v.z = src[(size_t)min(base + 4 * k + 2, IH - 1) * IW];
        v.w = src[(size_t)min(base + 4 * k + 3, IH - 1) * IW];
        *(float4*)(colp + 4 * k) = v;
      }
    }
  }
  __syncthreads();

  // x-pass into registers
  float xr[LROWS];
  #pragma unroll
  for (int r = 0; r < LROWS; ++r) xr[r] = 0.0f;
  if (t < OS) {
    const float4* W4 = (const float4*)(wtab + ((size_t)(b * 2 + 1) * 224 + t) * 8);
    float4 wA = W4[0], wB = W4[1];
    int ix0 = (int)wB.z;
    int nx  = (int)wB.w;
    #pragma unroll
    for (int j = 0; j < 6; ++j) {
      if (j < nx) {
        float wj = (j == 0) ? wA.x : (j == 1) ? wA.y : (j == 2) ? wA.z
                 : (j == 3) ? wA.w : (j == 4) ? wB.x : wB.y;
        const float* colp = s_mem + (ix0 + j) * CSTRIDE;
        #pragma unroll
        for (int k = 0; k < 6; ++k) {
          if (k < nchunk) {
            float4 f = *(const float4*)(colp + 4 * k);
            xr[4 * k + 0] += wj * f.x;
            xr[4 * k + 1] += wj * f.y;
            xr[4 * k + 2] += wj * f.z;
            xr[4 * k + 3] += wj * f.w;
          }
        }
      }
    }
  }

  // y-pass: dense 16x24 block-uniform matrix (scalar loads), zero LDS
  const float* M = My + (size_t)(b * NTILE + tile) * 16 * 24;
  float bfac = P[6];
  float psum = 0.0f;
  float* dst = xc + ((size_t)(b * NC + c) * OS + oyb) * OS + t;
  #pragma unroll
  for (int i = 0; i < TROWS; ++i) {
    float acc = 0.0f;
    #pragma unroll
    for (int r = 0; r < LROWS; ++r) acc += M[i * 24 + r] * xr[r];
    if (t < OS) {
      dst[(size_t)i * OS] = acc;
      psum += fminf(fmaxf(acc * bfac, 0.0f), 1.0f);
    }
  }
  for (int off = 32; off > 0; off >>= 1) psum += __shfl_down(psum, off, 64);
  int wid = t >> 6, lane = t & 63;
  if (lane == 0) wsum[wid] = psum;
  __syncthreads();
  if (t == 0) rowsum[blk] = wsum[0] + wsum[1] + wsum[2] + wsum[3];
}

__global__ __launch_bounds__(64) void k_means(const float* __restrict__ rowsum,
                                              float* __restrict__ means) {
  int b = blockIdx.x, t = threadIdx.x;
  float acc = 0.0f;
  if (t < NC * NTILE) {
    int c = t / NTILE;
    float w = (c == 0) ? 0.2989f : ((c == 1) ? 0.587f : 0.114f);
    acc = w * rowsum[b * NC * NTILE + t];
  }
  for (int off = 32; off > 0; off >>= 1) acc += __shfl_down(acc, off, 64);
  if (t == 0) means[b] = acc / (float)PIX;
}

// ---------------- color jitter ----------------
__device__ __forceinline__ float clip01(float x) { return fminf(fmaxf(x, 0.0f), 1.0f); }
__device__ __forceinline__ float fmod1(float x)  { return x - floorf(x); }

__device__ __forceinline__ void jitter_px(float& r, float& g, float& bb,
                                          float mg, float bfac, float cfac,
                                          float sfac, float hfac) {
  r = clip01(r * bfac); g = clip01(g * bfac); bb = clip01(bb * bfac);
  r  = clip01(cfac * r  + (1.0f - cfac) * mg);
  g  = clip01(cfac * g  + (1.0f - cfac) * mg);
  bb = clip01(cfac * bb + (1.0f - cfac) * mg);
  float gray = 0.2989f * r + 0.587f * g + 0.114f * bb;
  r  = clip01(sfac * r  + (1.0f - sfac) * gray);
  g  = clip01(sfac * g  + (1.0f - sfac) * gray);
  bb = clip01(sfac * bb + (1.0f - sfac) * gray);
  float maxc = fmaxf(r, fmaxf(g, bb));
  float minc = fminf(r, fminf(g, bb));
  float v = maxc, d = maxc - minc;
  float s = (maxc > 0.0f) ? (d / maxc) : 0.0f;
  float dn = (d > 0.0f) ? d : 1.0f;
  float rc = (maxc - r) / dn, gc = (maxc - g) / dn, bc2 = (maxc - bb) / dn;
  float h = (maxc == r) ? (bc2 - gc)
          : ((maxc == g) ? (2.0f + rc - bc2) : (4.0f + gc - rc));
  h = (d > 0.0f) ? fmod1(h / 6.0f) : 0.0f;
  h = fmod1(h + hfac);
  float fi = floorf(h * 6.0f);
  float f = h * 6.0f - fi;
  int i = ((int)fi) % 6;
  float pp = v * (1.0f - s);
  float q  = v * (1.0f - s * f);
  float tt = v * (1.0f - s * (1.0f - f));
  switch (i) {
    case 0: r = v;  g = tt; bb = pp; break;
    case 1: r = q;  g = v;  bb = pp; break;
    case 2: r = pp; g = v;  bb = tt; break;
    case 3: r = pp; g = q;  bb = v;  break;
    case 4: r = tt; g = pp; bb = v;  break;
    default: r = v; g = pp; bb = q;  break;
  }
}

// float4: 4 px/thread. Blur batches -> bf16 xj buffer; non-blur -> f32 out.
__global__ __launch_bounds__(256) void k_jitter(const float* __restrict__ xc,
                                                const float* __restrict__ means,
                                                const float* __restrict__ prm,
                                                unsigned short* __restrict__ xjb,
                                                float* __restrict__ out) {
  int idx = blockIdx.x * 256 + threadIdx.x;
  const int QPB = PIX / 4;
  if (idx >= NB * QPB) return;
  int b = idx / QPB, p4 = idx - b * QPB;
  const float* P = prm + b * PSTRIDE;
  float bfac = P[6], cfac = P[7], sfac = P[8], hfac = P[9];
  bool cj = P[10] != 0.0f;
  bool bl = P[11] != 0.0f;
  size_t base4 = ((size_t)b * NC * PIX) / 4 + p4;
  const float4* in4 = (const float4*)xc;
  float4 r4 = in4[base4];
  float4 g4 = in4[base4 + PIX / 4];
  float4 b4 = in4[base4 + 2 * (PIX / 4)];
  if (cj) {
    float mg = means[b];
    float* rp = (float*)&r4; float* gp = (float*)&g4; float* bp = (float*)&b4;
    #pragma unroll
    for (int k = 0; k < 4; ++k) jitter_px(rp[k], gp[k], bp[k], mg, bfac, cfac, sfac, hfac);
  }
  if (bl) {
    ushort4* dst = (ushort4*)xjb;
    ushort4 s;
    s.x = f2bf(r4.x); s.y = f2bf(r4.y); s.z = f2bf(r4.z); s.w = f2bf(r4.w);
    dst[base4] = s;
    s.x = f2bf(g4.x); s.y = f2bf(g4.y); s.z = f2bf(g4.z); s.w = f2bf(g4.w);
    dst[base4 + PIX / 4] = s;
    s.x = f2bf(b4.x); s.y = f2bf(b4.y); s.z = f2bf(b4.z); s.w = f2bf(b4.w);
    dst[base4 + 2 * (PIX / 4)] = s;
  } else {
    float4* dst4 = (float4*)out;
    dst4[base4] = r4;
    dst4[base4 + PIX / 4] = g4;
    dst4[base4 + 2 * (PIX / 4)] = b4;
  }
}

// ---------------- fused separable gaussian blur (reflect), gated per b -----
__global__ __launch_bounds__(256) void k_blur(const unsigned short* __restrict__ xjb,
                                              float* __restrict__ out,
                                              const float* __restrict__ prm) {
  int blk = blockIdx.x;
  int tile = blk % NTILE;
  int c = (blk / NTILE) % NC;
  int b = blk / (NTILE * NC);
  const float* P = prm + b * PSTRIDE;
  if (P[11] == 0.0f) return;
  int t = threadIdx.x;
  int oyb = tile * TROWS;

  __shared__ float s_in[TROWS + 14][OS];
  __shared__ float s_mid[TROWS][OS];
  __shared__ float s_k[15];
  if (t < 15) s_k[t] = P[12 + t];

  const ushort4* plane4 = (const ushort4*)(xjb + (size_t)(b * NC + c) * PIX);
  float* oplane = out + (size_t)(b * NC + c) * PIX;
  {
    float4* s4 = (float4*)&s_in[0][0];
    const int RQ = OS / 4;                       // 56 quads per row
    for (int f = t; f < (TROWS + 14) * RQ; f += 256) {
      int r = f / RQ, col4 = f - r * RQ;
      int yy = oyb - 7 + r;
      yy = (yy < 0) ? -yy : ((yy > OS - 1) ? (2 * (OS - 1) - yy) : yy);
      ushort4 q = plane4[yy * RQ + col4];
      s4[f] = make_float4(bf2f(q.x), bf2f(q.y), bf2f(q.z), bf2f(q.w));
    }
  }
  __syncthreads();
  if (t < OS) {
    for (int i = 0; i < TROWS; ++i) {
      float acc = 0.0f;
      #pragma unroll
      for (int k = 0; k < 15; ++k) acc += s_k[k] * s_in[i + k][t];
      s_mid[i][t] = acc;
    }
  }
  __syncthreads();
  if (t < OS) {
    for (int i = 0; i < TROWS; ++i) {
      float acc = 0.0f;
      #pragma unroll
      for (int k = 0; k < 15; ++k) {
        int xx = t - 7 + k;
        xx = (xx < 0) ? -xx : ((xx > OS - 1) ? (2 * (OS - 1) - xx) : xx);
        acc += s_k[k] * s_mid[i][xx];
      }
      oplane[(size_t)(oyb + i) * OS + t] = acc;
    }
  }
}

// ---------------- launch ----------------
extern "C" void kernel_launch(void* const* d_in, const int* in_sizes, int n_in,
                              void* d_out, int out_size, void* d_ws, size_t ws_size,
                              hipStream_t stream) {
  const float* x = (const float*)d_in[0];
  float* out = (float*)d_out;
  char* ws = (char*)d_ws;

  float* prm    = (float*)ws;                            // 32768 B
  float* rowsum = (float*)(ws + 32768);                  // 43008 B
  float* means  = (float*)(ws + 75776);                  // 1024 B
  float* wtab   = (float*)(ws + 76800);                  // 3670016 B
  float* My     = (float*)(ws + 3746816);                // 256*14*384*4 = 5505024 B
  unsigned short* xjb = (unsigned short*)(ws + 9251840); // 77070336 B (bf16 xj)

  k_params<<<1, 256, 0, stream>>>(prm);
  k_weights<<<NB * 2, 224, 0, stream>>>(prm, wtab);
  k_ymat<<<NB * NTILE, 384, 0, stream>>>(wtab, My);

  int nblk = NB * NC * NTILE;                            // 10752
  k_resize<<<nblk, 256, 0, stream>>>(x, out, rowsum, prm, wtab, My);  // xc -> d_out
  k_means<<<NB, 64, 0, stream>>>(rowsum, means);

  int nquad = NB * (PIX / 4);                            // 3211264
  k_jitter<<<(nquad + 255) / 256, 256, 0, stream>>>(out, means, prm, xjb, out);

  k_blur<<<nblk, 256, 0, stream>>>(xjb, out, prm);       // blurred b: xjb -> out
}

// Round 6
// 386.552 us; speedup vs baseline: 1.0619x; 1.0619x over previous
//
#include <hip/hip_runtime.h>
#include <cstdint>
#include <cstddef>

// ============================================================================
// MildAugmentStage: random-resized-crop (cubic, antialias) + color jitter +
// separable gaussian blur, reproducing jax.random (threefry2x32) exactly.
// Round 5: y-pass fully in registers via readfirstlane(ry0) + bounded static
// case dispatch (no LDS, no global matrix); col-major b128 staging kept.
// ============================================================================

#define JAX_PARTITIONABLE 1

#define NB 256
#define NC 3
#define IH 256
#define IW 256
#define OS 224
#define PIX (OS * OS)         // 50176
#define PSTRIDE 32
#define TROWS 16              // output rows per resize/blur tile
#define LROWS 24              // max staged input rows
#define NTILE 14              // 224/16
#define CSTRIDE 28            // dwords per staged column (112 B)

// ---------------- bf16 helpers ----------------
__device__ __forceinline__ float bf2f(unsigned short u) {
  return __uint_as_float(((unsigned)u) << 16);
}
__device__ __forceinline__ unsigned short f2bf(float f) {
  unsigned u = __float_as_uint(f);
  return (unsigned short)((u + 0x7FFFu + ((u >> 16) & 1u)) >> 16);
}

// ---------------- threefry-2x32 ----------------
__device__ __forceinline__ void tf2x32(uint32_t k0, uint32_t k1,
                                       uint32_t x0, uint32_t x1,
                                       uint32_t& o0, uint32_t& o1) {
  uint32_t ks[3] = {k0, k1, k0 ^ k1 ^ 0x1BD11BDAu};
  uint32_t a = x0 + ks[0], b = x1 + ks[1];
  const int R[2][4] = {{13, 15, 26, 6}, {17, 29, 16, 24}};
  #pragma unroll
  for (int i = 0; i < 5; ++i) {
    #pragma unroll
    for (int j = 0; j < 4; ++j) {
      int r = R[i & 1][j];
      a += b;
      b = (b << r) | (b >> (32 - r));
      b ^= a;
    }
    a += ks[(i + 1) % 3];
    b += ks[(i + 2) % 3] + (uint32_t)(i + 1);
  }
  o0 = a; o1 = b;
}

__device__ __forceinline__ float bits_to_u01(uint32_t bits) {
  uint32_t fb = (bits >> 9) | 0x3f800000u;
  return __uint_as_float(fb) - 1.0f;
}

__device__ __forceinline__ float u01_n(uint32_t k0, uint32_t k1, uint32_t i, uint32_t N) {
#if JAX_PARTITIONABLE
  uint32_t a, b; tf2x32(k0, k1, 0u, i, a, b);
  return bits_to_u01(a ^ b);
#else
  uint32_t half = N >> 1;
  uint32_t a, b;
  if (i < half) { tf2x32(k0, k1, i, half + i, a, b); return bits_to_u01(a); }
  tf2x32(k0, k1, i - half, i, a, b); return bits_to_u01(b);
#endif
}

__device__ __forceinline__ float junif(uint32_t k0, uint32_t k1, uint32_t i, uint32_t N,
                                       float mn, float mx) {
  float u = u01_n(k0, k1, i, N);
  float d = __fsub_rn(mx, mn);
  float r = __fadd_rn(__fmul_rn(u, d), mn);
  return fmaxf(mn, r);
}

// ---------------- per-batch augmentation parameters ----------------
__global__ __launch_bounds__(256) void k_params(float* __restrict__ prm) {
  int b = threadIdx.x;
  if (b >= NB) return;
  uint32_t ks[10][2];
#if JAX_PARTITIONABLE
  for (int j = 0; j < 10; ++j) tf2x32(0u, 42u, 0u, (uint32_t)j, ks[j][0], ks[j][1]);
#else
  {
    uint32_t flat[20];
    for (int j = 0; j < 10; ++j) {
      uint32_t a, bb; tf2x32(0u, 42u, (uint32_t)j, (uint32_t)(10 + j), a, bb);
      flat[j] = a; flat[10 + j] = bb;
    }
    for (int j = 0; j < 10; ++j) { ks[j][0] = flat[2 * j]; ks[j][1] = flat[2 * j + 1]; }
  }
#endif
  float* P = prm + b * PSTRIDE;

  float uarea = junif(ks[0][0], ks[0][1], b, NB, 0.8f, 1.0f);
  float area  = __fmul_rn(65536.0f, uarea);
  float lmn = (float)(-0.28768207245178085);
  float lmx = (float)( 0.28768207245178085);
  float ur  = junif(ks[1][0], ks[1][1], b, NB, lmn, lmx);
  float ratio = (float)exp((double)ur);

  float cw = rintf(__fsqrt_rn(__fmul_rn(area, ratio)));
  cw = fminf(fmaxf(cw, 1.0f), 256.0f);
  float ch = rintf(__fsqrt_rn(__fdiv_rn(area, ratio)));
  ch = fminf(fmaxf(ch, 1.0f), 256.0f);

  float ui = u01_n(ks[2][0], ks[2][1], b, NB);
  float uj = u01_n(ks[3][0], ks[3][1], b, NB);
  float i0 = floorf(__fmul_rn(ui, __fadd_rn(__fsub_rn(256.0f, ch), 1.0f)));
  float j0 = floorf(__fmul_rn(uj, __fadd_rn(__fsub_rn(256.0f, cw), 1.0f)));

  float sy = __fdiv_rn(224.0f, ch), sx = __fdiv_rn(224.0f, cw);
  float ty = -__fmul_rn(i0, sy),   tx = -__fmul_rn(j0, sx);
  float inv_sy = __fdiv_rn(1.0f, sy), inv_sx = __fdiv_rn(1.0f, sx);
  P[0] = inv_sy;
  P[1] = __fmul_rn(ty, inv_sy);
  P[2] = fmaxf(inv_sy, 1.0f);
  P[3] = inv_sx;
  P[4] = __fmul_rn(tx, inv_sx);
  P[5] = fmaxf(inv_sx, 1.0f);

  P[6] = junif(ks[4][0], ks[4][1], b, NB, 0.9f, 1.1f);
  P[7] = junif(ks[5][0], ks[5][1], b, NB, 0.9f, 1.1f);
  P[8] = junif(ks[6][0], ks[6][1], b, NB, 0.9f, 1.1f);
  P[9] = junif(ks[7][0], ks[7][1], b, NB, -0.01f, 0.01f);
  P[10] = (u01_n(ks[8][0], ks[8][1], b, NB) < 0.8f) ? 1.0f : 0.0f;

  uint32_t kb0[2], kb1[2];
#if JAX_PARTITIONABLE
  tf2x32(ks[9][0], ks[9][1], 0u, 0u, kb0[0], kb0[1]);
  tf2x32(ks[9][0], ks[9][1], 0u, 1u, kb1[0], kb1[1]);
#else
  {
    uint32_t f0, s0, f1, s1;
    tf2x32(ks[9][0], ks[9][1], 0u, 2u, f0, s0);
    tf2x32(ks[9][0], ks[9][1], 1u, 3u, f1, s1);
    kb0[0] = f0; kb0[1] = f1; kb1[0] = s0; kb1[1] = s1;
  }
#endif
  float sg = junif(kb0[0], kb0[1], b, NB, 0.1f, 2.0f);
  P[11] = (u01_n(kb1[0], kb1[1], b, NB) < 0.5f) ? 1.0f : 0.0f;

  float e[15]; float ssum = 0.0f;
  for (int k = 0; k < 15; ++k) {
    float t = (float)k - 7.0f;
    float z = t / sg;
    e[k] = expf(-0.5f * (z * z));
    ssum += e[k];
  }
  for (int k = 0; k < 15; ++k) P[12 + k] = e[k] / ssum;
}

// ---------------- cubic (Keys, a=-0.5) ----------------
__device__ __forceinline__ float keys_cubic(float x) {
  float o = ((1.5f * x - 2.5f) * x) * x + 1.0f;
  if (x >= 1.0f) o = ((-0.5f * x + 2.5f) * x - 4.0f) * x + 2.0f;
  if (x >= 2.0f) o = 0.0f;
  return o;
}

// ---------------- per-batch resize weight tables ----------------
// wtab[b][dim(0=y,1=x)][o][8]: w0..w5 (zero-padded), i0, ntaps
__global__ __launch_bounds__(224) void k_weights(const float* __restrict__ prm,
                                                 float* __restrict__ wtab) {
  int o = threadIdx.x;
  int dim = blockIdx.x & 1;
  int b = blockIdx.x >> 1;
  const float* P = prm + b * PSTRIDE;
  float inv = dim ? P[3] : P[0];
  float ti  = dim ? P[4] : P[1];
  float ks  = dim ? P[5] : P[2];
  float sf = ((float)o + 0.5f) * inv - ti - 0.5f;
  float r = 2.0f * ks;
  int i0 = max(0, (int)ceilf(sf - r));
  int i1 = min(255, (int)floorf(sf + r));
  int n = i1 - i0 + 1; if (n > 6) n = 6;
  float w[6]; float tot = 0.0f;
  #pragma unroll
  for (int j = 0; j < 6; ++j) {
    float v = 0.0f;
    if (j < n) { float d = fabsf(sf - (float)(i0 + j)) / ks; v = keys_cubic(d); }
    w[j] = v; tot += v;
  }
  float ri = (fabsf(tot) > 1.1920929e-4f) ? (1.0f / tot) : 0.0f;
  float* W = wtab + ((size_t)(b * 2 + dim) * 224 + o) * 8;
  #pragma unroll
  for (int j = 0; j < 6; ++j) W[j] = w[j] * ri;
  W[6] = (float)i0;
  W[7] = (float)n;
}

// ---------------- tiled separable resize (x in LDS cols, y in registers) ---
__global__ __launch_bounds__(256) void k_resize(const float* __restrict__ x,
                                                float* __restrict__ xc,
                                                float* __restrict__ rowsum,
                                                const float* __restrict__ prm,
                                                const float* __restrict__ wtab) {
  int blk = blockIdx.x;
  int tile = blk % NTILE;
  int c = (blk / NTILE) % NC;
  int b = blk / (NTILE * NC);
  int t = threadIdx.x;
  int oyb = tile * TROWS;
  const float* P = prm + b * PSTRIDE;
  const float* wty = wtab + ((size_t)(b * 2) * 224 + oyb) * 8;

  __shared__ __align__(16) float s_mem[256 * CSTRIDE];   // 28672 B col-major
  __shared__ float wsum[4];

  // uniform tile geometry (broadcast loads, forced scalar via readfirstlane)
  float4 h0 = *(const float4*)(wty + 4);            // row0: w4,w5,iy0,n
  float4 hL = *(const float4*)(wty + 15 * 8 + 4);   // row15
  int base = __builtin_amdgcn_readfirstlane((int)h0.z);
  int last = __builtin_amdgcn_readfirstlane((int)hL.z);
  int rows = min(last + 6, IH) - base; if (rows > LROWS) rows = LROWS;
  int nchunk = (rows + 3) >> 2;                     // uniform, <=6

  // stage column t: nchunk chunks of 4 rows, b128 writes at col*28 + 4k dwords
  {
    const float* src = x + (size_t)(b * NC + c) * IH * IW + t;
    float* colp = s_mem + t * CSTRIDE;
    #pragma unroll
    for (int k = 0; k < 6; ++k) {
      if (k < nchunk) {
        float4 v;
        v.x = src[(size_t)min(base + 4 * k + 0, IH - 1) * IW];
        v.y = src[(size_t)min(base + 4 * k + 1, IH - 1) * IW];
        v.z = src[(size_t)min(base + 4 * k + 2, IH - 1) * IW];
        v.w = src[(size_t)min(base + 4 * k + 3, IH - 1) * IW];
        *(float4*)(colp + 4 * k) = v;
      }
    }
  }
  __syncthreads();

  // x-pass into registers: always 6 taps (zero-padded weights are exact)
  float xr[LROWS];
  #pragma unroll
  for (int r = 0; r < LROWS; ++r) xr[r] = 0.0f;
  if (t < OS) {
    const float4* W4 = (const float4*)(wtab + ((size_t)(b * 2 + 1) * 224 + t) * 8);
    float4 wA = W4[0], wB = W4[1];
    int ix0 = (int)wB.z;
    #pragma unroll
    for (int j = 0; j < 6; ++j) {
      float wj = (j == 0) ? wA.x : (j == 1) ? wA.y : (j == 2) ? wA.z
               : (j == 3) ? wA.w : (j == 4) ? wB.x : wB.y;
      const float* colp = s_mem + (ix0 + j) * CSTRIDE;
      #pragma unroll
      for (int k = 0; k < 6; ++k) {
        if (k < nchunk) {
          float4 f = *(const float4*)(colp + 4 * k);
          xr[4 * k + 0] += wj * f.x;
          xr[4 * k + 1] += wj * f.y;
          xr[4 * k + 2] += wj * f.z;
          xr[4 * k + 3] += wj * f.w;
        }
      }
    }
  }

  // y-pass: registers only. ry0 is block-uniform; dispatch over the provable
  // bound ry0(i) in [max(0,7i/8-3), min(18, (8i+6)/7+1)] with static indices.
  float bfac = P[6];
  float psum = 0.0f;
  float* dst = xc + ((size_t)(b * NC + c) * OS + oyb) * OS + t;
  #pragma unroll
  for (int i = 0; i < TROWS; ++i) {
    float4 a = *(const float4*)(wty + i * 8);       // w0..w3
    float4 h = *(const float4*)(wty + i * 8 + 4);   // w4,w5,iy0,n
    int ry0 = __builtin_amdgcn_readfirstlane((int)h.z) - base;
    const int RLO = ((7 * i) / 8 >= 3) ? (7 * i) / 8 - 3 : 0;
    const int RHI = (((8 * i + 6) / 7 + 1) <= 18) ? ((8 * i + 6) / 7 + 1) : 18;
    float acc = 0.0f;
    #pragma unroll
    for (int rr = RLO; rr <= RHI; ++rr) {
      if (rr == ry0) {
        acc = a.x * xr[rr + 0] + a.y * xr[rr + 1] + a.z * xr[rr + 2]
            + a.w * xr[rr + 3] + h.x * xr[rr + 4] + h.y * xr[rr + 5];
      }
    }
    if (t < OS) {
      dst[(size_t)i * OS] = acc;
      psum += fminf(fmaxf(acc * bfac, 0.0f), 1.0f);
    }
  }
  for (int off = 32; off > 0; off >>= 1) psum += __shfl_down(psum, off, 64);
  int wid = t >> 6, lane = t & 63;
  if (lane == 0) wsum[wid] = psum;
  __syncthreads();
  if (t == 0) rowsum[blk] = wsum[0] + wsum[1] + wsum[2] + wsum[3];
}

__global__ __launch_bounds__(64) void k_means(const float* __restrict__ rowsum,
                                              float* __restrict__ means) {
  int b = blockIdx.x, t = threadIdx.x;
  float acc = 0.0f;
  if (t < NC * NTILE) {
    int c = t / NTILE;
    float w = (c == 0) ? 0.2989f : ((c == 1) ? 0.587f : 0.114f);
    acc = w * rowsum[b * NC * NTILE + t];
  }
  for (int off = 32; off > 0; off >>= 1) acc += __shfl_down(acc, off, 64);
  if (t == 0) means[b] = acc / (float)PIX;
}

// ---------------- color jitter ----------------
__device__ __forceinline__ float clip01(float x) { return fminf(fmaxf(x, 0.0f), 1.0f); }
__device__ __forceinline__ float fmod1(float x)  { return x - floorf(x); }

__device__ __forceinline__ void jitter_px(float& r, float& g, float& bb,
                                          float mg, float bfac, float cfac,
                                          float sfac, float hfac) {
  r = clip01(r * bfac); g = clip01(g * bfac); bb = clip01(bb * bfac);
  r  = clip01(cfac * r  + (1.0f - cfac) * mg);
  g  = clip01(cfac * g  + (1.0f - cfac) * mg);
  bb = clip01(cfac * bb + (1.0f - cfac) * mg);
  float gray = 0.2989f * r + 0.587f * g + 0.114f * bb;
  r  = clip01(sfac * r  + (1.0f - sfac) * gray);
  g  = clip01(sfac * g  + (1.0f - sfac) * gray);
  bb = clip01(sfac * bb + (1.0f - sfac) * gray);
  float maxc = fmaxf(r, fmaxf(g, bb));
  float minc = fminf(r, fminf(g, bb));
  float v = maxc, d = maxc - minc;
  float s = (maxc > 0.0f) ? (d / maxc) : 0.0f;
  float dn = (d > 0.0f) ? d : 1.0f;
  float rc = (maxc - r) / dn, gc = (maxc - g) / dn, bc2 = (maxc - bb) / dn;
  float h = (maxc == r) ? (bc2 - gc)
          : ((maxc == g) ? (2.0f + rc - bc2) : (4.0f + gc - rc));
  h = (d > 0.0f) ? fmod1(h / 6.0f) : 0.0f;
  h = fmod1(h + hfac);
  float fi = floorf(h * 6.0f);
  float f = h * 6.0f - fi;
  int i = ((int)fi) % 6;
  float pp = v * (1.0f - s);
  float q  = v * (1.0f - s * f);
  float tt = v * (1.0f - s * (1.0f - f));
  switch (i) {
    case 0: r = v;  g = tt; bb = pp; break;
    case 1: r = q;  g = v;  bb = pp; break;
    case 2: r = pp; g = v;  bb = tt; break;
    case 3: r = pp; g = q;  bb = v;  break;
    case 4: r = tt; g = pp; bb = v;  break;
    default: r = v; g = pp; bb = q;  break;
  }
}

// float4: 4 px/thread. Blur batches -> bf16 xj buffer; non-blur -> f32 out.
__global__ __launch_bounds__(256) void k_jitter(const float* __restrict__ xc,
                                                const float* __restrict__ means,
                                                const float* __restrict__ prm,
                                                unsigned short* __restrict__ xjb,
                                                float* __restrict__ out) {
  int idx = blockIdx.x * 256 + threadIdx.x;
  const int QPB = PIX / 4;
  if (idx >= NB * QPB) return;
  int b = idx / QPB, p4 = idx - b * QPB;
  const float* P = prm + b * PSTRIDE;
  float bfac = P[6], cfac = P[7], sfac = P[8], hfac = P[9];
  bool cj = P[10] != 0.0f;
  bool bl = P[11] != 0.0f;
  size_t base4 = ((size_t)b * NC * PIX) / 4 + p4;
  const float4* in4 = (const float4*)xc;
  float4 r4 = in4[base4];
  float4 g4 = in4[base4 + PIX / 4];
  float4 b4 = in4[base4 + 2 * (PIX / 4)];
  if (cj) {
    float mg = means[b];
    float* rp = (float*)&r4; float* gp = (float*)&g4; float* bp = (float*)&b4;
    #pragma unroll
    for (int k = 0; k < 4; ++k) jitter_px(rp[k], gp[k], bp[k], mg, bfac, cfac, sfac, hfac);
  }
  if (bl) {
    ushort4* dst = (ushort4*)xjb;
    ushort4 s;
    s.x = f2bf(r4.x); s.y = f2bf(r4.y); s.z = f2bf(r4.z); s.w = f2bf(r4.w);
    dst[base4] = s;
    s.x = f2bf(g4.x); s.y = f2bf(g4.y); s.z = f2bf(g4.z); s.w = f2bf(g4.w);
    dst[base4 + PIX / 4] = s;
    s.x = f2bf(b4.x); s.y = f2bf(b4.y); s.z = f2bf(b4.z); s.w = f2bf(b4.w);
    dst[base4 + 2 * (PIX / 4)] = s;
  } else {
    float4* dst4 = (float4*)out;
    dst4[base4] = r4;
    dst4[base4 + PIX / 4] = g4;
    dst4[base4 + 2 * (PIX / 4)] = b4;
  }
}

// ---------------- fused separable gaussian blur (reflect), gated per b -----
__global__ __launch_bounds__(256) void k_blur(const unsigned short* __restrict__ xjb,
                                              float* __restrict__ out,
                                              const float* __restrict__ prm) {
  int blk = blockIdx.x;
  int tile = blk % NTILE;
  int c = (blk / NTILE) % NC;
  int b = blk / (NTILE * NC);
  const float* P = prm + b * PSTRIDE;
  if (P[11] == 0.0f) return;
  int t = threadIdx.x;
  int oyb = tile * TROWS;

  __shared__ float s_in[TROWS + 14][OS];
  __shared__ float s_mid[TROWS][OS];
  __shared__ float s_k[15];
  if (t < 15) s_k[t] = P[12 + t];

  const ushort4* plane4 = (const ushort4*)(xjb + (size_t)(b * NC + c) * PIX);
  float* oplane = out + (size_t)(b * NC + c) * PIX;
  {
    float4* s4 = (float4*)&s_in[0][0];
    const int RQ = OS / 4;                       // 56 quads per row
    for (int f = t; f < (TROWS + 14) * RQ; f += 256) {
      int r = f / RQ, col4 = f - r * RQ;
      int yy = oyb - 7 + r;
      yy = (yy < 0) ? -yy : ((yy > OS - 1) ? (2 * (OS - 1) - yy) : yy);
      ushort4 q = plane4[yy * RQ + col4];
      s4[f] = make_float4(bf2f(q.x), bf2f(q.y), bf2f(q.z), bf2f(q.w));
    }
  }
  __syncthreads();
  if (t < OS) {
    for (int i = 0; i < TROWS; ++i) {
      float acc = 0.0f;
      #pragma unroll
      for (int k = 0; k < 15; ++k) acc += s_k[k] * s_in[i + k][t];
      s_mid[i][t] = acc;
    }
  }
  __syncthreads();
  if (t < OS) {
    for (int i = 0; i < TROWS; ++i) {
      float acc = 0.0f;
      #pragma unroll
      for (int k = 0; k < 15; ++k) {
        int xx = t - 7 + k;
        xx = (xx < 0) ? -xx : ((xx > OS - 1) ? (2 * (OS - 1) - xx) : xx);
        acc += s_k[k] * s_mid[i][xx];
      }
      oplane[(size_t)(oyb + i) * OS + t] = acc;
    }
  }
}

// ---------------- launch ----------------
extern "C" void kernel_launch(void* const* d_in, const int* in_sizes, int n_in,
                              void* d_out, int out_size, void* d_ws, size_t ws_size,
                              hipStream_t stream) {
  const float* x = (const float*)d_in[0];
  float* out = (float*)d_out;
  char* ws = (char*)d_ws;

  float* prm    = (float*)ws;                            // 32768 B
  float* rowsum = (float*)(ws + 32768);                  // 43008 B
  float* means  = (float*)(ws + 75776);                  // 1024 B
  float* wtab   = (float*)(ws + 76800);                  // 3670016 B
  unsigned short* xjb = (unsigned short*)(ws + 3746816); // 77070336 B (bf16 xj)

  k_params<<<1, 256, 0, stream>>>(prm);
  k_weights<<<NB * 2, 224, 0, stream>>>(prm, wtab);

  int nblk = NB * NC * NTILE;                            // 10752
  k_resize<<<nblk, 256, 0, stream>>>(x, out, rowsum, prm, wtab);  // xc -> d_out
  k_means<<<NB, 64, 0, stream>>>(rowsum, means);

  int nquad = NB * (PIX / 4);                            // 3211264
  k_jitter<<<(nquad + 255) / 256, 256, 0, stream>>>(out, means, prm, xjb, out);

  k_blur<<<nblk, 256, 0, stream>>>(xjb, out, prm);       // blurred b: xjb -> out
}

// Round 7
// 358.649 us; speedup vs baseline: 1.1445x; 1.0778x over previous
//
#include <hip/hip_runtime.h>
#include <cstdint>
#include <cstddef>

// ============================================================================
// MildAugmentStage: random-resized-crop (cubic, antialias) + color jitter +
// separable gaussian blur, reproducing jax.random (threefry2x32) exactly.
// Round 6: round-2 skeleton, LDS-cheap passes: col-major b128 staging/x-pass,
// stride-25 col-major y buffer (write2/read2, conflict-free), y-weights via
// LDS broadcast with partial unroll (no VGPR hoisting, no per-lane VMEM).
// ============================================================================

#define JAX_PARTITIONABLE 1

#define NB 256
#define NC 3
#define IH 256
#define IW 256
#define OS 224
#define PIX (OS * OS)         // 50176
#define PSTRIDE 32
#define TROWS 16              // output rows per resize/blur tile
#define LROWS 24              // max staged input rows
#define NTILE 14              // 224/16
#define CSTRIDE 28            // dwords per staged column (112 B)
#define YSTR 25               // y-buffer column stride (gcd(25,32)=1)

// ---------------- bf16 helpers ----------------
__device__ __forceinline__ float bf2f(unsigned short u) {
  return __uint_as_float(((unsigned)u) << 16);
}
__device__ __forceinline__ unsigned short f2bf(float f) {
  unsigned u = __float_as_uint(f);
  return (unsigned short)((u + 0x7FFFu + ((u >> 16) & 1u)) >> 16);
}

// ---------------- threefry-2x32 ----------------
__device__ __forceinline__ void tf2x32(uint32_t k0, uint32_t k1,
                                       uint32_t x0, uint32_t x1,
                                       uint32_t& o0, uint32_t& o1) {
  uint32_t ks[3] = {k0, k1, k0 ^ k1 ^ 0x1BD11BDAu};
  uint32_t a = x0 + ks[0], b = x1 + ks[1];
  const int R[2][4] = {{13, 15, 26, 6}, {17, 29, 16, 24}};
  #pragma unroll
  for (int i = 0; i < 5; ++i) {
    #pragma unroll
    for (int j = 0; j < 4; ++j) {
      int r = R[i & 1][j];
      a += b;
      b = (b << r) | (b >> (32 - r));
      b ^= a;
    }
    a += ks[(i + 1) % 3];
    b += ks[(i + 2) % 3] + (uint32_t)(i + 1);
  }
  o0 = a; o1 = b;
}

__device__ __forceinline__ float bits_to_u01(uint32_t bits) {
  uint32_t fb = (bits >> 9) | 0x3f800000u;
  return __uint_as_float(fb) - 1.0f;
}

__device__ __forceinline__ float u01_n(uint32_t k0, uint32_t k1, uint32_t i, uint32_t N) {
#if JAX_PARTITIONABLE
  uint32_t a, b; tf2x32(k0, k1, 0u, i, a, b);
  return bits_to_u01(a ^ b);
#else
  uint32_t half = N >> 1;
  uint32_t a, b;
  if (i < half) { tf2x32(k0, k1, i, half + i, a, b); return bits_to_u01(a); }
  tf2x32(k0, k1, i - half, i, a, b); return bits_to_u01(b);
#endif
}

__device__ __forceinline__ float junif(uint32_t k0, uint32_t k1, uint32_t i, uint32_t N,
                                       float mn, float mx) {
  float u = u01_n(k0, k1, i, N);
  float d = __fsub_rn(mx, mn);
  float r = __fadd_rn(__fmul_rn(u, d), mn);
  return fmaxf(mn, r);
}

// ---------------- per-batch augmentation parameters ----------------
__global__ __launch_bounds__(256) void k_params(float* __restrict__ prm) {
  int b = threadIdx.x;
  if (b >= NB) return;
  uint32_t ks[10][2];
#if JAX_PARTITIONABLE
  for (int j = 0; j < 10; ++j) tf2x32(0u, 42u, 0u, (uint32_t)j, ks[j][0], ks[j][1]);
#else
  {
    uint32_t flat[20];
    for (int j = 0; j < 10; ++j) {
      uint32_t a, bb; tf2x32(0u, 42u, (uint32_t)j, (uint32_t)(10 + j), a, bb);
      flat[j] = a; flat[10 + j] = bb;
    }
    for (int j = 0; j < 10; ++j) { ks[j][0] = flat[2 * j]; ks[j][1] = flat[2 * j + 1]; }
  }
#endif
  float* P = prm + b * PSTRIDE;

  float uarea = junif(ks[0][0], ks[0][1], b, NB, 0.8f, 1.0f);
  float area  = __fmul_rn(65536.0f, uarea);
  float lmn = (float)(-0.28768207245178085);
  float lmx = (float)( 0.28768207245178085);
  float ur  = junif(ks[1][0], ks[1][1], b, NB, lmn, lmx);
  float ratio = (float)exp((double)ur);

  float cw = rintf(__fsqrt_rn(__fmul_rn(area, ratio)));
  cw = fminf(fmaxf(cw, 1.0f), 256.0f);
  float ch = rintf(__fsqrt_rn(__fdiv_rn(area, ratio)));
  ch = fminf(fmaxf(ch, 1.0f), 256.0f);

  float ui = u01_n(ks[2][0], ks[2][1], b, NB);
  float uj = u01_n(ks[3][0], ks[3][1], b, NB);
  float i0 = floorf(__fmul_rn(ui, __fadd_rn(__fsub_rn(256.0f, ch), 1.0f)));
  float j0 = floorf(__fmul_rn(uj, __fadd_rn(__fsub_rn(256.0f, cw), 1.0f)));

  float sy = __fdiv_rn(224.0f, ch), sx = __fdiv_rn(224.0f, cw);
  float ty = -__fmul_rn(i0, sy),   tx = -__fmul_rn(j0, sx);
  float inv_sy = __fdiv_rn(1.0f, sy), inv_sx = __fdiv_rn(1.0f, sx);
  P[0] = inv_sy;
  P[1] = __fmul_rn(ty, inv_sy);
  P[2] = fmaxf(inv_sy, 1.0f);
  P[3] = inv_sx;
  P[4] = __fmul_rn(tx, inv_sx);
  P[5] = fmaxf(inv_sx, 1.0f);

  P[6] = junif(ks[4][0], ks[4][1], b, NB, 0.9f, 1.1f);
  P[7] = junif(ks[5][0], ks[5][1], b, NB, 0.9f, 1.1f);
  P[8] = junif(ks[6][0], ks[6][1], b, NB, 0.9f, 1.1f);
  P[9] = junif(ks[7][0], ks[7][1], b, NB, -0.01f, 0.01f);
  P[10] = (u01_n(ks[8][0], ks[8][1], b, NB) < 0.8f) ? 1.0f : 0.0f;

  uint32_t kb0[2], kb1[2];
#if JAX_PARTITIONABLE
  tf2x32(ks[9][0], ks[9][1], 0u, 0u, kb0[0], kb0[1]);
  tf2x32(ks[9][0], ks[9][1], 0u, 1u, kb1[0], kb1[1]);
#else
  {
    uint32_t f0, s0, f1, s1;
    tf2x32(ks[9][0], ks[9][1], 0u, 2u, f0, s0);
    tf2x32(ks[9][0], ks[9][1], 1u, 3u, f1, s1);
    kb0[0] = f0; kb0[1] = f1; kb1[0] = s0; kb1[1] = s1;
  }
#endif
  float sg = junif(kb0[0], kb0[1], b, NB, 0.1f, 2.0f);
  P[11] = (u01_n(kb1[0], kb1[1], b, NB) < 0.5f) ? 1.0f : 0.0f;

  float e[15]; float ssum = 0.0f;
  for (int k = 0; k < 15; ++k) {
    float t = (float)k - 7.0f;
    float z = t / sg;
    e[k] = expf(-0.5f * (z * z));
    ssum += e[k];
  }
  for (int k = 0; k < 15; ++k) P[12 + k] = e[k] / ssum;
}

// ---------------- cubic (Keys, a=-0.5) ----------------
__device__ __forceinline__ float keys_cubic(float x) {
  float o = ((1.5f * x - 2.5f) * x) * x + 1.0f;
  if (x >= 1.0f) o = ((-0.5f * x + 2.5f) * x - 4.0f) * x + 2.0f;
  if (x >= 2.0f) o = 0.0f;
  return o;
}

// ---------------- per-batch resize weight tables ----------------
// wtab[b][dim(0=y,1=x)][o][8]: w0..w5 (zero-padded), i0, ntaps
__global__ __launch_bounds__(224) void k_weights(const float* __restrict__ prm,
                                                 float* __restrict__ wtab) {
  int o = threadIdx.x;
  int dim = blockIdx.x & 1;
  int b = blockIdx.x >> 1;
  const float* P = prm + b * PSTRIDE;
  float inv = dim ? P[3] : P[0];
  float ti  = dim ? P[4] : P[1];
  float ks  = dim ? P[5] : P[2];
  float sf = ((float)o + 0.5f) * inv - ti - 0.5f;
  float r = 2.0f * ks;
  int i0 = max(0, (int)ceilf(sf - r));
  int i1 = min(255, (int)floorf(sf + r));
  int n = i1 - i0 + 1; if (n > 6) n = 6;
  float w[6]; float tot = 0.0f;
  #pragma unroll
  for (int j = 0; j < 6; ++j) {
    float v = 0.0f;
    if (j < n) { float d = fabsf(sf - (float)(i0 + j)) / ks; v = keys_cubic(d); }
    w[j] = v; tot += v;
  }
  float ri = (fabsf(tot) > 1.1920929e-4f) ? (1.0f / tot) : 0.0f;
  float* W = wtab + ((size_t)(b * 2 + dim) * 224 + o) * 8;
  #pragma unroll
  for (int j = 0; j < 6; ++j) W[j] = w[j] * ri;
  W[6] = (float)i0;
  W[7] = (float)n;
}

// ---------------- tiled separable resize ----------------
// x-pass: col-major staged input, b128 column reads -> xr[24] registers
// y-pass: stride-25 col-major LDS buffer, read2-pair reads, broadcast weights
__global__ __launch_bounds__(256) void k_resize(const float* __restrict__ x,
                                                float* __restrict__ xc,
                                                float* __restrict__ rowsum,
                                                const float* __restrict__ prm,
                                                const float* __restrict__ wtab) {
  int blk = blockIdx.x;
  int tile = blk % NTILE;
  int c = (blk / NTILE) % NC;
  int b = blk / (NTILE * NC);
  int t = threadIdx.x;
  int oyb = tile * TROWS;
  const float* P = prm + b * PSTRIDE;
  const float* wty = wtab + ((size_t)(b * 2) * 224 + oyb) * 8;

  __shared__ __align__(16) float s_mem[256 * CSTRIDE];   // 28672 B
  __shared__ __align__(16) float s_wyl[TROWS * 8];       // 512 B y-weight block
  __shared__ float wsum[4];

  // copy this tile's y-weight block to LDS (one coalesced read)
  if (t < TROWS * 8) s_wyl[t] = wty[t];

  // uniform geometry (same-address loads -> broadcast)
  int base = (int)wty[6];
  int last = (int)wty[15 * 8 + 6];
  int rows = min(last + 6, IH) - base; if (rows > LROWS) rows = LROWS;
  int nchunk = (rows + 3) >> 2;                 // uniform, 5..6

  // stage column t: nchunk chunks of 4 rows, b128 writes at col*28 + 4k dwords
  {
    const float* src = x + (size_t)(b * NC + c) * IH * IW + t;
    float* colp = s_mem + t * CSTRIDE;
    #pragma unroll
    for (int k = 0; k < 6; ++k) {
      if (k < nchunk) {
        float4 v;
        v.x = src[(size_t)min(base + 4 * k + 0, IH - 1) * IW];
        v.y = src[(size_t)min(base + 4 * k + 1, IH - 1) * IW];
        v.z = src[(size_t)min(base + 4 * k + 2, IH - 1) * IW];
        v.w = src[(size_t)min(base + 4 * k + 3, IH - 1) * IW];
        *(float4*)(colp + 4 * k) = v;
      }
    }
  }
  __syncthreads();

  // x-pass into registers: always 6 taps (zero-padded weights are exact)
  float xr[LROWS];
  #pragma unroll
  for (int r = 0; r < LROWS; ++r) xr[r] = 0.0f;
  if (t < OS) {
    const float4* W4 = (const float4*)(wtab + ((size_t)(b * 2 + 1) * 224 + t) * 8);
    float4 wA = W4[0], wB = W4[1];
    int ix0 = (int)wB.z;
    #pragma unroll
    for (int j = 0; j < 6; ++j) {
      float wj = (j == 0) ? wA.x : (j == 1) ? wA.y : (j == 2) ? wA.z
               : (j == 3) ? wA.w : (j == 4) ? wB.x : wB.y;
      const float* colp = s_mem + (ix0 + j) * CSTRIDE;
      #pragma unroll
      for (int k = 0; k < 6; ++k) {
        if (k < nchunk) {
          float4 f = *(const float4*)(colp + 4 * k);
          xr[4 * k + 0] += wj * f.x;
          xr[4 * k + 1] += wj * f.y;
          xr[4 * k + 2] += wj * f.z;
          xr[4 * k + 3] += wj * f.w;
        }
      }
    }
  }
  __syncthreads();

  // writeback col-major stride 25 (conflict-free; merges into ds_write2_b32)
  if (t < OS) {
    float* colq = s_mem + t * YSTR;
    #pragma unroll
    for (int r = 0; r < LROWS; ++r) colq[r] = xr[r];
  }
  __syncthreads();

  // y-pass: broadcast weights from LDS, contiguous column reads (read2 pairs)
  float bfac = P[6];
  float psum = 0.0f;
  float* dst = xc + ((size_t)(b * NC + c) * OS + oyb) * OS + t;
  const float* colq = s_mem + t * YSTR;
  #pragma unroll 4
  for (int i = 0; i < TROWS; ++i) {
    float4 a = *(const float4*)&s_wyl[i * 8];       // w0..w3 (broadcast b128)
    float4 h = *(const float4*)&s_wyl[i * 8 + 4];   // w4,w5,iy0,n
    int ry0 = (int)h.z - base;
    const float* p = colq + ry0;
    float acc = a.x * p[0] + a.y * p[1] + a.z * p[2]
              + a.w * p[3] + h.x * p[4] + h.y * p[5];
    if (t < OS) {
      dst[(size_t)i * OS] = acc;
      psum += fminf(fmaxf(acc * bfac, 0.0f), 1.0f);
    }
  }
  for (int off = 32; off > 0; off >>= 1) psum += __shfl_down(psum, off, 64);
  int wid = t >> 6, lane = t & 63;
  if (lane == 0) wsum[wid] = psum;
  __syncthreads();
  if (t == 0) rowsum[blk] = wsum[0] + wsum[1] + wsum[2] + wsum[3];
}

__global__ __launch_bounds__(64) void k_means(const float* __restrict__ rowsum,
                                              float* __restrict__ means) {
  int b = blockIdx.x, t = threadIdx.x;
  float acc = 0.0f;
  if (t < NC * NTILE) {
    int c = t / NTILE;
    float w = (c == 0) ? 0.2989f : ((c == 1) ? 0.587f : 0.114f);
    acc = w * rowsum[b * NC * NTILE + t];
  }
  for (int off = 32; off > 0; off >>= 1) acc += __shfl_down(acc, off, 64);
  if (t == 0) means[b] = acc / (float)PIX;
}

// ---------------- color jitter ----------------
__device__ __forceinline__ float clip01(float x) { return fminf(fmaxf(x, 0.0f), 1.0f); }
__device__ __forceinline__ float fmod1(float x)  { return x - floorf(x); }

__device__ __forceinline__ void jitter_px(float& r, float& g, float& bb,
                                          float mg, float bfac, float cfac,
                                          float sfac, float hfac) {
  r = clip01(r * bfac); g = clip01(g * bfac); bb = clip01(bb * bfac);
  r  = clip01(cfac * r  + (1.0f - cfac) * mg);
  g  = clip01(cfac * g  + (1.0f - cfac) * mg);
  bb = clip01(cfac * bb + (1.0f - cfac) * mg);
  float gray = 0.2989f * r + 0.587f * g + 0.114f * bb;
  r  = clip01(sfac * r  + (1.0f - sfac) * gray);
  g  = clip01(sfac * g  + (1.0f - sfac) * gray);
  bb = clip01(sfac * bb + (1.0f - sfac) * gray);
  float maxc = fmaxf(r, fmaxf(g, bb));
  float minc = fminf(r, fminf(g, bb));
  float v = maxc, d = maxc - minc;
  float s = (maxc > 0.0f) ? (d / maxc) : 0.0f;
  float dn = (d > 0.0f) ? d : 1.0f;
  float rc = (maxc - r) / dn, gc = (maxc - g) / dn, bc2 = (maxc - bb) / dn;
  float h = (maxc == r) ? (bc2 - gc)
          : ((maxc == g) ? (2.0f + rc - bc2) : (4.0f + gc - rc));
  h = (d > 0.0f) ? fmod1(h / 6.0f) : 0.0f;
  h = fmod1(h + hfac);
  float fi = floorf(h * 6.0f);
  float f = h * 6.0f - fi;
  int i = ((int)fi) % 6;
  float pp = v * (1.0f - s);
  float q  = v * (1.0f - s * f);
  float tt = v * (1.0f - s * (1.0f - f));
  switch (i) {
    case 0: r = v;  g = tt; bb = pp; break;
    case 1: r = q;  g = v;  bb = pp; break;
    case 2: r = pp; g = v;  bb = tt; break;
    case 3: r = pp; g = q;  bb = v;  break;
    case 4: r = tt; g = pp; bb = v;  break;
    default: r = v; g = pp; bb = q;  break;
  }
}

// float4: 4 px/thread. Blur batches -> bf16 xj buffer; non-blur -> f32 out.
__global__ __launch_bounds__(256) void k_jitter(const float* __restrict__ xc,
                                                const float* __restrict__ means,
                                                const float* __restrict__ prm,
                                                unsigned short* __restrict__ xjb,
                                                float* __restrict__ out) {
  int idx = blockIdx.x * 256 + threadIdx.x;
  const int QPB = PIX / 4;
  if (idx >= NB * QPB) return;
  int b = idx / QPB, p4 = idx - b * QPB;
  const float* P = prm + b * PSTRIDE;
  float bfac = P[6], cfac = P[7], sfac = P[8], hfac = P[9];
  bool cj = P[10] != 0.0f;
  bool bl = P[11] != 0.0f;
  size_t base4 = ((size_t)b * NC * PIX) / 4 + p4;
  const float4* in4 = (const float4*)xc;
  float4 r4 = in4[base4];
  float4 g4 = in4[base4 + PIX / 4];
  float4 b4 = in4[base4 + 2 * (PIX / 4)];
  if (cj) {
    float mg = means[b];
    float* rp = (float*)&r4; float* gp = (float*)&g4; float* bp = (float*)&b4;
    #pragma unroll
    for (int k = 0; k < 4; ++k) jitter_px(rp[k], gp[k], bp[k], mg, bfac, cfac, sfac, hfac);
  }
  if (bl) {
    ushort4* dst = (ushort4*)xjb;
    ushort4 s;
    s.x = f2bf(r4.x); s.y = f2bf(r4.y); s.z = f2bf(r4.z); s.w = f2bf(r4.w);
    dst[base4] = s;
    s.x = f2bf(g4.x); s.y = f2bf(g4.y); s.z = f2bf(g4.z); s.w = f2bf(g4.w);
    dst[base4 + PIX / 4] = s;
    s.x = f2bf(b4.x); s.y = f2bf(b4.y); s.z = f2bf(b4.z); s.w = f2bf(b4.w);
    dst[base4 + 2 * (PIX / 4)] = s;
  } else {
    float4* dst4 = (float4*)out;
    dst4[base4] = r4;
    dst4[base4 + PIX / 4] = g4;
    dst4[base4 + 2 * (PIX / 4)] = b4;
  }
}

// ---------------- fused separable gaussian blur (reflect), gated per b -----
__global__ __launch_bounds__(256) void k_blur(const unsigned short* __restrict__ xjb,
                                              float* __restrict__ out,
                                              const float* __restrict__ prm) {
  int blk = blockIdx.x;
  int tile = blk % NTILE;
  int c = (blk / NTILE) % NC;
  int b = blk / (NTILE * NC);
  const float* P = prm + b * PSTRIDE;
  if (P[11] == 0.0f) return;
  int t = threadIdx.x;
  int oyb = tile * TROWS;

  __shared__ float s_in[TROWS + 14][OS];
  __shared__ float s_mid[TROWS][OS];
  __shared__ float s_k[15];
  if (t < 15) s_k[t] = P[12 + t];

  const ushort4* plane4 = (const ushort4*)(xjb + (size_t)(b * NC + c) * PIX);
  float* oplane = out + (size_t)(b * NC + c) * PIX;
  {
    float4* s4 = (float4*)&s_in[0][0];
    const int RQ = OS / 4;                       // 56 quads per row
    for (int f = t; f < (TROWS + 14) * RQ; f += 256) {
      int r = f / RQ, col4 = f - r * RQ;
      int yy = oyb - 7 + r;
      yy = (yy < 0) ? -yy : ((yy > OS - 1) ? (2 * (OS - 1) - yy) : yy);
      ushort4 q = plane4[yy * RQ + col4];
      s4[f] = make_float4(bf2f(q.x), bf2f(q.y), bf2f(q.z), bf2f(q.w));
    }
  }
  __syncthreads();
  if (t < OS) {
    for (int i = 0; i < TROWS; ++i) {
      float acc = 0.0f;
      #pragma unroll
      for (int k = 0; k < 15; ++k) acc += s_k[k] * s_in[i + k][t];
      s_mid[i][t] = acc;
    }
  }
  __syncthreads();
  if (t < OS) {
    for (int i = 0; i < TROWS; ++i) {
      float acc = 0.0f;
      #pragma unroll
      for (int k = 0; k < 15; ++k) {
        int xx = t - 7 + k;
        xx = (xx < 0) ? -xx : ((xx > OS - 1) ? (2 * (OS - 1) - xx) : xx);
        acc += s_k[k] * s_mid[i][xx];
      }
      oplane[(size_t)(oyb + i) * OS + t] = acc;
    }
  }
}

// ---------------- launch ----------------
extern "C" void kernel_launch(void* const* d_in, const int* in_sizes, int n_in,
                              void* d_out, int out_size, void* d_ws, size_t ws_size,
                              hipStream_t stream) {
  const float* x = (const float*)d_in[0];
  float* out = (float*)d_out;
  char* ws = (char*)d_ws;

  float* prm    = (float*)ws;                            // 32768 B
  float* rowsum = (float*)(ws + 32768);                  // 43008 B
  float* means  = (float*)(ws + 75776);                  // 1024 B
  float* wtab   = (float*)(ws + 76800);                  // 3670016 B
  unsigned short* xjb = (unsigned short*)(ws + 3746816); // 77070336 B (bf16 xj)

  k_params<<<1, 256, 0, stream>>>(prm);
  k_weights<<<NB * 2, 224, 0, stream>>>(prm, wtab);

  int nblk = NB * NC * NTILE;                            // 10752
  k_resize<<<nblk, 256, 0, stream>>>(x, out, rowsum, prm, wtab);  // xc -> d_out
  k_means<<<NB, 64, 0, stream>>>(rowsum, means);

  int nquad = NB * (PIX / 4);                            // 3211264
  k_jitter<<<(nquad + 255) / 256, 256, 0, stream>>>(out, means, prm, xjb, out);

  k_blur<<<nblk, 256, 0, stream>>>(xjb, out, prm);       // blurred b: xjb -> out
}

// Round 8
// 197.060 us; speedup vs baseline: 2.0830x; 1.8200x over previous
//
#include <hip/hip_runtime.h>
#include <cstdint>
#include <cstddef>

// ============================================================================
// MildAugmentStage: random-resized-crop (cubic, antialias) + color jitter +
// separable gaussian blur, reproducing jax.random (threefry2x32) exactly.
// Round 7: fixed trip counts everywhere (no runtime guards in unrolled loops
// -> low VGPR, rounds 4-6 lesson), col-major b128 staging/x-pass (round 3),
// stride-25 y-buffer with write2/read2 + LDS-broadcast weights (round 6).
// ============================================================================

#define JAX_PARTITIONABLE 1

#define NB 256
#define NC 3
#define IH 256
#define IW 256
#define OS 224
#define PIX (OS * OS)         // 50176
#define PSTRIDE 32
#define TROWS 16              // output rows per resize/blur tile
#define LROWS 24              // max staged input rows
#define NTILE 14              // 224/16
#define CSTRIDE 28            // dwords per staged column (112 B)
#define YSTR 25               // y-buffer column stride (gcd(25,32)=1)

// ---------------- bf16 helpers ----------------
__device__ __forceinline__ float bf2f(unsigned short u) {
  return __uint_as_float(((unsigned)u) << 16);
}
__device__ __forceinline__ unsigned short f2bf(float f) {
  unsigned u = __float_as_uint(f);
  return (unsigned short)((u + 0x7FFFu + ((u >> 16) & 1u)) >> 16);
}

// ---------------- threefry-2x32 ----------------
__device__ __forceinline__ void tf2x32(uint32_t k0, uint32_t k1,
                                       uint32_t x0, uint32_t x1,
                                       uint32_t& o0, uint32_t& o1) {
  uint32_t ks[3] = {k0, k1, k0 ^ k1 ^ 0x1BD11BDAu};
  uint32_t a = x0 + ks[0], b = x1 + ks[1];
  const int R[2][4] = {{13, 15, 26, 6}, {17, 29, 16, 24}};
  #pragma unroll
  for (int i = 0; i < 5; ++i) {
    #pragma unroll
    for (int j = 0; j < 4; ++j) {
      int r = R[i & 1][j];
      a += b;
      b = (b << r) | (b >> (32 - r));
      b ^= a;
    }
    a += ks[(i + 1) % 3];
    b += ks[(i + 2) % 3] + (uint32_t)(i + 1);
  }
  o0 = a; o1 = b;
}

__device__ __forceinline__ float bits_to_u01(uint32_t bits) {
  uint32_t fb = (bits >> 9) | 0x3f800000u;
  return __uint_as_float(fb) - 1.0f;
}

__device__ __forceinline__ float u01_n(uint32_t k0, uint32_t k1, uint32_t i, uint32_t N) {
#if JAX_PARTITIONABLE
  uint32_t a, b; tf2x32(k0, k1, 0u, i, a, b);
  return bits_to_u01(a ^ b);
#else
  uint32_t half = N >> 1;
  uint32_t a, b;
  if (i < half) { tf2x32(k0, k1, i, half + i, a, b); return bits_to_u01(a); }
  tf2x32(k0, k1, i - half, i, a, b); return bits_to_u01(b);
#endif
}

__device__ __forceinline__ float junif(uint32_t k0, uint32_t k1, uint32_t i, uint32_t N,
                                       float mn, float mx) {
  float u = u01_n(k0, k1, i, N);
  float d = __fsub_rn(mx, mn);
  float r = __fadd_rn(__fmul_rn(u, d), mn);
  return fmaxf(mn, r);
}

// ---------------- per-batch augmentation parameters ----------------
__global__ __launch_bounds__(256) void k_params(float* __restrict__ prm) {
  int b = threadIdx.x;
  if (b >= NB) return;
  uint32_t ks[10][2];
#if JAX_PARTITIONABLE
  for (int j = 0; j < 10; ++j) tf2x32(0u, 42u, 0u, (uint32_t)j, ks[j][0], ks[j][1]);
#else
  {
    uint32_t flat[20];
    for (int j = 0; j < 10; ++j) {
      uint32_t a, bb; tf2x32(0u, 42u, (uint32_t)j, (uint32_t)(10 + j), a, bb);
      flat[j] = a; flat[10 + j] = bb;
    }
    for (int j = 0; j < 10; ++j) { ks[j][0] = flat[2 * j]; ks[j][1] = flat[2 * j + 1]; }
  }
#endif
  float* P = prm + b * PSTRIDE;

  float uarea = junif(ks[0][0], ks[0][1], b, NB, 0.8f, 1.0f);
  float area  = __fmul_rn(65536.0f, uarea);
  float lmn = (float)(-0.28768207245178085);
  float lmx = (float)( 0.28768207245178085);
  float ur  = junif(ks[1][0], ks[1][1], b, NB, lmn, lmx);
  float ratio = (float)exp((double)ur);

  float cw = rintf(__fsqrt_rn(__fmul_rn(area, ratio)));
  cw = fminf(fmaxf(cw, 1.0f), 256.0f);
  float ch = rintf(__fsqrt_rn(__fdiv_rn(area, ratio)));
  ch = fminf(fmaxf(ch, 1.0f), 256.0f);

  float ui = u01_n(ks[2][0], ks[2][1], b, NB);
  float uj = u01_n(ks[3][0], ks[3][1], b, NB);
  float i0 = floorf(__fmul_rn(ui, __fadd_rn(__fsub_rn(256.0f, ch), 1.0f)));
  float j0 = floorf(__fmul_rn(uj, __fadd_rn(__fsub_rn(256.0f, cw), 1.0f)));

  float sy = __fdiv_rn(224.0f, ch), sx = __fdiv_rn(224.0f, cw);
  float ty = -__fmul_rn(i0, sy),   tx = -__fmul_rn(j0, sx);
  float inv_sy = __fdiv_rn(1.0f, sy), inv_sx = __fdiv_rn(1.0f, sx);
  P[0] = inv_sy;
  P[1] = __fmul_rn(ty, inv_sy);
  P[2] = fmaxf(inv_sy, 1.0f);
  P[3] = inv_sx;
  P[4] = __fmul_rn(tx, inv_sx);
  P[5] = fmaxf(inv_sx, 1.0f);

  P[6] = junif(ks[4][0], ks[4][1], b, NB, 0.9f, 1.1f);
  P[7] = junif(ks[5][0], ks[5][1], b, NB, 0.9f, 1.1f);
  P[8] = junif(ks[6][0], ks[6][1], b, NB, 0.9f, 1.1f);
  P[9] = junif(ks[7][0], ks[7][1], b, NB, -0.01f, 0.01f);
  P[10] = (u01_n(ks[8][0], ks[8][1], b, NB) < 0.8f) ? 1.0f : 0.0f;

  uint32_t kb0[2], kb1[2];
#if JAX_PARTITIONABLE
  tf2x32(ks[9][0], ks[9][1], 0u, 0u, kb0[0], kb0[1]);
  tf2x32(ks[9][0], ks[9][1], 0u, 1u, kb1[0], kb1[1]);
#else
  {
    uint32_t f0, s0, f1, s1;
    tf2x32(ks[9][0], ks[9][1], 0u, 2u, f0, s0);
    tf2x32(ks[9][0], ks[9][1], 1u, 3u, f1, s1);
    kb0[0] = f0; kb0[1] = f1; kb1[0] = s0; kb1[1] = s1;
  }
#endif
  float sg = junif(kb0[0], kb0[1], b, NB, 0.1f, 2.0f);
  P[11] = (u01_n(kb1[0], kb1[1], b, NB) < 0.5f) ? 1.0f : 0.0f;

  float e[15]; float ssum = 0.0f;
  for (int k = 0; k < 15; ++k) {
    float t = (float)k - 7.0f;
    float z = t / sg;
    e[k] = expf(-0.5f * (z * z));
    ssum += e[k];
  }
  for (int k = 0; k < 15; ++k) P[12 + k] = e[k] / ssum;
}

// ---------------- cubic (Keys, a=-0.5) ----------------
__device__ __forceinline__ float keys_cubic(float x) {
  float o = ((1.5f * x - 2.5f) * x) * x + 1.0f;
  if (x >= 1.0f) o = ((-0.5f * x + 2.5f) * x - 4.0f) * x + 2.0f;
  if (x >= 2.0f) o = 0.0f;
  return o;
}

// ---------------- per-batch resize weight tables ----------------
// wtab[b][dim(0=y,1=x)][o][8]: w0..w5 (zero-padded), i0, ntaps
__global__ __launch_bounds__(224) void k_weights(const float* __restrict__ prm,
                                                 float* __restrict__ wtab) {
  int o = threadIdx.x;
  int dim = blockIdx.x & 1;
  int b = blockIdx.x >> 1;
  const float* P = prm + b * PSTRIDE;
  float inv = dim ? P[3] : P[0];
  float ti  = dim ? P[4] : P[1];
  float ks  = dim ? P[5] : P[2];
  float sf = ((float)o + 0.5f) * inv - ti - 0.5f;
  float r = 2.0f * ks;
  int i0 = max(0, (int)ceilf(sf - r));
  int i1 = min(255, (int)floorf(sf + r));
  int n = i1 - i0 + 1; if (n > 6) n = 6;
  float w[6]; float tot = 0.0f;
  #pragma unroll
  for (int j = 0; j < 6; ++j) {
    float v = 0.0f;
    if (j < n) { float d = fabsf(sf - (float)(i0 + j)) / ks; v = keys_cubic(d); }
    w[j] = v; tot += v;
  }
  float ri = (fabsf(tot) > 1.1920929e-4f) ? (1.0f / tot) : 0.0f;
  float* W = wtab + ((size_t)(b * 2 + dim) * 224 + o) * 8;
  #pragma unroll
  for (int j = 0; j < 6; ++j) W[j] = w[j] * ri;
  W[6] = (float)i0;
  W[7] = (float)n;
}

// ---------------- tiled separable resize ----------------
// staging: col-major, FIXED 6 chunks of 4 rows (clamped) -> 6 ds_write_b128
// x-pass:  FIXED 6 taps x 6 chunks -> 36 ds_read_b128 (zero-pad weights exact)
// y-pass:  stride-25 col buffer (write2/read2, conflict-free), LDS bcast wts
__global__ __launch_bounds__(256) void k_resize(const float* __restrict__ x,
                                                float* __restrict__ xc,
                                                float* __restrict__ rowsum,
                                                const float* __restrict__ prm,
                                                const float* __restrict__ wtab) {
  int blk = blockIdx.x;
  int tile = blk % NTILE;
  int c = (blk / NTILE) % NC;
  int b = blk / (NTILE * NC);
  int t = threadIdx.x;
  int oyb = tile * TROWS;
  const float* P = prm + b * PSTRIDE;
  const float* wty = wtab + ((size_t)(b * 2) * 224 + oyb) * 8;

  __shared__ __align__(16) float s_mem[256 * CSTRIDE];   // 28672 B
  __shared__ __align__(16) float s_wyl[TROWS * 8];       // 512 B y-weight block
  __shared__ float wsum[4];

  // copy tile's y-weight block to LDS (one coalesced read)
  if (t < TROWS * 8) s_wyl[t] = wty[t];

  // uniform geometry (same-address load -> broadcast)
  int base = (int)wty[6];

  // stage column t: FIXED 6 chunks of 4 rows (row-clamped), b128 writes
  {
    const float* src = x + (size_t)(b * NC + c) * IH * IW + t;
    float* colp = s_mem + t * CSTRIDE;
    #pragma unroll
    for (int k = 0; k < 6; ++k) {
      float4 v;
      v.x = src[(size_t)min(base + 4 * k + 0, IH - 1) * IW];
      v.y = src[(size_t)min(base + 4 * k + 1, IH - 1) * IW];
      v.z = src[(size_t)min(base + 4 * k + 2, IH - 1) * IW];
      v.w = src[(size_t)min(base + 4 * k + 3, IH - 1) * IW];
      *(float4*)(colp + 4 * k) = v;
    }
  }
  __syncthreads();

  // x-pass into registers: FIXED 6 taps (zero-padded weights are exact)
  float xr[LROWS];
  #pragma unroll
  for (int r = 0; r < LROWS; ++r) xr[r] = 0.0f;
  if (t < OS) {
    const float4* W4 = (const float4*)(wtab + ((size_t)(b * 2 + 1) * 224 + t) * 8);
    float4 wA = W4[0], wB = W4[1];
    int ix0 = (int)wB.z;
    #pragma unroll
    for (int j = 0; j < 6; ++j) {
      float wj = (j == 0) ? wA.x : (j == 1) ? wA.y : (j == 2) ? wA.z
               : (j == 3) ? wA.w : (j == 4) ? wB.x : wB.y;
      const float* colp = s_mem + (ix0 + j) * CSTRIDE;
      #pragma unroll
      for (int k = 0; k < 6; ++k) {
        float4 f = *(const float4*)(colp + 4 * k);
        xr[4 * k + 0] += wj * f.x;
        xr[4 * k + 1] += wj * f.y;
        xr[4 * k + 2] += wj * f.z;
        xr[4 * k + 3] += wj * f.w;
      }
    }
  }
  __syncthreads();

  // writeback col-major stride 25 (conflict-free; merges to ds_write2_b32)
  {
    float* colq = s_mem + t * YSTR;
    #pragma unroll
    for (int r = 0; r < LROWS; ++r) colq[r] = xr[r];
  }
  __syncthreads();

  // y-pass: LDS-broadcast weights, contiguous column reads (ds_read2 pairs)
  float bfac = P[6];
  float psum = 0.0f;
  bool act = (t < OS);
  float* dst = xc + ((size_t)(b * NC + c) * OS + oyb) * OS + t;
  const float* colq = s_mem + t * YSTR;
  #pragma unroll 2
  for (int i = 0; i < TROWS; ++i) {
    float4 a = *(const float4*)&s_wyl[i * 8];       // w0..w3 (broadcast)
    float4 h = *(const float4*)&s_wyl[i * 8 + 4];   // w4,w5,iy0,n
    int ry0 = (int)h.z - base;
    const float* p = colq + ry0;
    float acc = a.x * p[0] + a.y * p[1] + a.z * p[2]
              + a.w * p[3] + h.x * p[4] + h.y * p[5];
    if (act) {
      dst[(size_t)i * OS] = acc;
      psum += fminf(fmaxf(acc * bfac, 0.0f), 1.0f);
    }
  }
  for (int off = 32; off > 0; off >>= 1) psum += __shfl_down(psum, off, 64);
  int wid = t >> 6, lane = t & 63;
  if (lane == 0) wsum[wid] = psum;
  __syncthreads();
  if (t == 0) rowsum[blk] = wsum[0] + wsum[1] + wsum[2] + wsum[3];
}

__global__ __launch_bounds__(64) void k_means(const float* __restrict__ rowsum,
                                              float* __restrict__ means) {
  int b = blockIdx.x, t = threadIdx.x;
  float acc = 0.0f;
  if (t < NC * NTILE) {
    int c = t / NTILE;
    float w = (c == 0) ? 0.2989f : ((c == 1) ? 0.587f : 0.114f);
    acc = w * rowsum[b * NC * NTILE + t];
  }
  for (int off = 32; off > 0; off >>= 1) acc += __shfl_down(acc, off, 64);
  if (t == 0) means[b] = acc / (float)PIX;
}

// ---------------- color jitter ----------------
__device__ __forceinline__ float clip01(float x) { return fminf(fmaxf(x, 0.0f), 1.0f); }
__device__ __forceinline__ float fmod1(float x)  { return x - floorf(x); }

__device__ __forceinline__ void jitter_px(float& r, float& g, float& bb,
                                          float mg, float bfac, float cfac,
                                          float sfac, float hfac) {
  r = clip01(r * bfac); g = clip01(g * bfac); bb = clip01(bb * bfac);
  r  = clip01(cfac * r  + (1.0f - cfac) * mg);
  g  = clip01(cfac * g  + (1.0f - cfac) * mg);
  bb = clip01(cfac * bb + (1.0f - cfac) * mg);
  float gray = 0.2989f * r + 0.587f * g + 0.114f * bb;
  r  = clip01(sfac * r  + (1.0f - sfac) * gray);
  g  = clip01(sfac * g  + (1.0f - sfac) * gray);
  bb = clip01(sfac * bb + (1.0f - sfac) * gray);
  float maxc = fmaxf(r, fmaxf(g, bb));
  float minc = fminf(r, fminf(g, bb));
  float v = maxc, d = maxc - minc;
  float s = (maxc > 0.0f) ? (d / maxc) : 0.0f;
  float dn = (d > 0.0f) ? d : 1.0f;
  float rc = (maxc - r) / dn, gc = (maxc - g) / dn, bc2 = (maxc - bb) / dn;
  float h = (maxc == r) ? (bc2 - gc)
          : ((maxc == g) ? (2.0f + rc - bc2) : (4.0f + gc - rc));
  h = (d > 0.0f) ? fmod1(h / 6.0f) : 0.0f;
  h = fmod1(h + hfac);
  float fi = floorf(h * 6.0f);
  float f = h * 6.0f - fi;
  int i = ((int)fi) % 6;
  float pp = v * (1.0f - s);
  float q  = v * (1.0f - s * f);
  float tt = v * (1.0f - s * (1.0f - f));
  switch (i) {
    case 0: r = v;  g = tt; bb = pp; break;
    case 1: r = q;  g = v;  bb = pp; break;
    case 2: r = pp; g = v;  bb = tt; break;
    case 3: r = pp; g = q;  bb = v;  break;
    case 4: r = tt; g = pp; bb = v;  break;
    default: r = v; g = pp; bb = q;  break;
  }
}

// float4: 4 px/thread. Blur batches -> bf16 xj buffer; non-blur -> f32 out.
__global__ __launch_bounds__(256) void k_jitter(const float* __restrict__ xc,
                                                const float* __restrict__ means,
                                                const float* __restrict__ prm,
                                                unsigned short* __restrict__ xjb,
                                                float* __restrict__ out) {
  int idx = blockIdx.x * 256 + threadIdx.x;
  const int QPB = PIX / 4;
  if (idx >= NB * QPB) return;
  int b = idx / QPB, p4 = idx - b * QPB;
  const float* P = prm + b * PSTRIDE;
  float bfac = P[6], cfac = P[7], sfac = P[8], hfac = P[9];
  bool cj = P[10] != 0.0f;
  bool bl = P[11] != 0.0f;
  size_t base4 = ((size_t)b * NC * PIX) / 4 + p4;
  const float4* in4 = (const float4*)xc;
  float4 r4 = in4[base4];
  float4 g4 = in4[base4 + PIX / 4];
  float4 b4 = in4[base4 + 2 * (PIX / 4)];
  if (cj) {
    float mg = means[b];
    float* rp = (float*)&r4; float* gp = (float*)&g4; float* bp = (float*)&b4;
    #pragma unroll
    for (int k = 0; k < 4; ++k) jitter_px(rp[k], gp[k], bp[k], mg, bfac, cfac, sfac, hfac);
  }
  if (bl) {
    ushort4* dst = (ushort4*)xjb;
    ushort4 s;
    s.x = f2bf(r4.x); s.y = f2bf(r4.y); s.z = f2bf(r4.z); s.w = f2bf(r4.w);
    dst[base4] = s;
    s.x = f2bf(g4.x); s.y = f2bf(g4.y); s.z = f2bf(g4.z); s.w = f2bf(g4.w);
    dst[base4 + PIX / 4] = s;
    s.x = f2bf(b4.x); s.y = f2bf(b4.y); s.z = f2bf(b4.z); s.w = f2bf(b4.w);
    dst[base4 + 2 * (PIX / 4)] = s;
  } else {
    float4* dst4 = (float4*)out;
    dst4[base4] = r4;
    dst4[base4 + PIX / 4] = g4;
    dst4[base4 + 2 * (PIX / 4)] = b4;
  }
}

// ---------------- fused separable gaussian blur (reflect), gated per b -----
__global__ __launch_bounds__(256) void k_blur(const unsigned short* __restrict__ xjb,
                                              float* __restrict__ out,
                                              const float* __restrict__ prm) {
  int blk = blockIdx.x;
  int tile = blk % NTILE;
  int c = (blk / NTILE) % NC;
  int b = blk / (NTILE * NC);
  const float* P = prm + b * PSTRIDE;
  if (P[11] == 0.0f) return;
  int t = threadIdx.x;
  int oyb = tile * TROWS;

  __shared__ float s_in[TROWS + 14][OS];
  __shared__ float s_mid[TROWS][OS];
  __shared__ float s_k[15];
  if (t < 15) s_k[t] = P[12 + t];

  const ushort4* plane4 = (const ushort4*)(xjb + (size_t)(b * NC + c) * PIX);
  float* oplane = out + (size_t)(b * NC + c) * PIX;
  {
    float4* s4 = (float4*)&s_in[0][0];
    const int RQ = OS / 4;                       // 56 quads per row
    for (int f = t; f < (TROWS + 14) * RQ; f += 256) {
      int r = f / RQ, col4 = f - r * RQ;
      int yy = oyb - 7 + r;
      yy = (yy < 0) ? -yy : ((yy > OS - 1) ? (2 * (OS - 1) - yy) : yy);
      ushort4 q = plane4[yy * RQ + col4];
      s4[f] = make_float4(bf2f(q.x), bf2f(q.y), bf2f(q.z), bf2f(q.w));
    }
  }
  __syncthreads();
  if (t < OS) {
    for (int i = 0; i < TROWS; ++i) {
      float acc = 0.0f;
      #pragma unroll
      for (int k = 0; k < 15; ++k) acc += s_k[k] * s_in[i + k][t];
      s_mid[i][t] = acc;
    }
  }
  __syncthreads();
  if (t < OS) {
    for (int i = 0; i < TROWS; ++i) {
      float acc = 0.0f;
      #pragma unroll
      for (int k = 0; k < 15; ++k) {
        int xx = t - 7 + k;
        xx = (xx < 0) ? -xx : ((xx > OS - 1) ? (2 * (OS - 1) - xx) : xx);
        acc += s_k[k] * s_mid[i][xx];
      }
      oplane[(size_t)(oyb + i) * OS + t] = acc;
    }
  }
}

// ---------------- launch ----------------
extern "C" void kernel_launch(void* const* d_in, const int* in_sizes, int n_in,
                              void* d_out, int out_size, void* d_ws, size_t ws_size,
                              hipStream_t stream) {
  const float* x = (const float*)d_in[0];
  float* out = (float*)d_out;
  char* ws = (char*)d_ws;

  float* prm    = (float*)ws;                            // 32768 B
  float* rowsum = (float*)(ws + 32768);                  // 43008 B
  float* means  = (float*)(ws + 75776);                  // 1024 B
  float* wtab   = (float*)(ws + 76800);                  // 3670016 B
  unsigned short* xjb = (unsigned short*)(ws + 3746816); // 77070336 B (bf16 xj)

  k_params<<<1, 256, 0, stream>>>(prm);
  k_weights<<<NB * 2, 224, 0, stream>>>(prm, wtab);

  int nblk = NB * NC * NTILE;                            // 10752
  k_resize<<<nblk, 256, 0, stream>>>(x, out, rowsum, prm, wtab);  // xc -> d_out
  k_means<<<NB, 64, 0, stream>>>(rowsum, means);

  int nquad = NB * (PIX / 4);                            // 3211264
  k_jitter<<<(nquad + 255) / 256, 256, 0, stream>>>(out, means, prm, xjb, out);

  k_blur<<<nblk, 256, 0, stream>>>(xjb, out, prm);       // blurred b: xjb -> out
}

// Round 9
// 170.335 us; speedup vs baseline: 2.4098x; 1.1569x over previous
//
#include <hip/hip_runtime.h>
#include <cstdint>
#include <cstddef>

// ============================================================================
// MildAugmentStage: random-resized-crop (cubic, antialias) + color jitter +
// separable gaussian blur, reproducing jax.random (threefry2x32) exactly.
// Round 8: bf16 xc/xj single in-place buffer (ws 81 MB), blur y-pass via
// contribution trick (static acc[16], bit-identical order), bf16 blur staging,
// weights in VGPRs. Resize structure unchanged from round 7 (proven).
// ============================================================================

#define JAX_PARTITIONABLE 1

#define NB 256
#define NC 3
#define IH 256
#define IW 256
#define OS 224
#define PIX (OS * OS)         // 50176
#define PSTRIDE 32
#define TROWS 16              // output rows per resize/blur tile
#define LROWS 24              // max staged input rows
#define NTILE 14              // 224/16
#define CSTRIDE 28            // dwords per staged column (112 B)
#define YSTR 25               // y-buffer column stride (gcd(25,32)=1)

// ---------------- bf16 helpers ----------------
__device__ __forceinline__ float bf2f(unsigned short u) {
  return __uint_as_float(((unsigned)u) << 16);
}
__device__ __forceinline__ unsigned short f2bf(float f) {
  unsigned u = __float_as_uint(f);
  return (unsigned short)((u + 0x7FFFu + ((u >> 16) & 1u)) >> 16);
}

// ---------------- threefry-2x32 ----------------
__device__ __forceinline__ void tf2x32(uint32_t k0, uint32_t k1,
                                       uint32_t x0, uint32_t x1,
                                       uint32_t& o0, uint32_t& o1) {
  uint32_t ks[3] = {k0, k1, k0 ^ k1 ^ 0x1BD11BDAu};
  uint32_t a = x0 + ks[0], b = x1 + ks[1];
  const int R[2][4] = {{13, 15, 26, 6}, {17, 29, 16, 24}};
  #pragma unroll
  for (int i = 0; i < 5; ++i) {
    #pragma unroll
    for (int j = 0; j < 4; ++j) {
      int r = R[i & 1][j];
      a += b;
      b = (b << r) | (b >> (32 - r));
      b ^= a;
    }
    a += ks[(i + 1) % 3];
    b += ks[(i + 2) % 3] + (uint32_t)(i + 1);
  }
  o0 = a; o1 = b;
}

__device__ __forceinline__ float bits_to_u01(uint32_t bits) {
  uint32_t fb = (bits >> 9) | 0x3f800000u;
  return __uint_as_float(fb) - 1.0f;
}

__device__ __forceinline__ float u01_n(uint32_t k0, uint32_t k1, uint32_t i, uint32_t N) {
#if JAX_PARTITIONABLE
  uint32_t a, b; tf2x32(k0, k1, 0u, i, a, b);
  return bits_to_u01(a ^ b);
#else
  uint32_t half = N >> 1;
  uint32_t a, b;
  if (i < half) { tf2x32(k0, k1, i, half + i, a, b); return bits_to_u01(a); }
  tf2x32(k0, k1, i - half, i, a, b); return bits_to_u01(b);
#endif
}

__device__ __forceinline__ float junif(uint32_t k0, uint32_t k1, uint32_t i, uint32_t N,
                                       float mn, float mx) {
  float u = u01_n(k0, k1, i, N);
  float d = __fsub_rn(mx, mn);
  float r = __fadd_rn(__fmul_rn(u, d), mn);
  return fmaxf(mn, r);
}

// ---------------- per-batch augmentation parameters ----------------
__global__ __launch_bounds__(256) void k_params(float* __restrict__ prm) {
  int b = threadIdx.x;
  if (b >= NB) return;
  uint32_t ks[10][2];
#if JAX_PARTITIONABLE
  for (int j = 0; j < 10; ++j) tf2x32(0u, 42u, 0u, (uint32_t)j, ks[j][0], ks[j][1]);
#else
  {
    uint32_t flat[20];
    for (int j = 0; j < 10; ++j) {
      uint32_t a, bb; tf2x32(0u, 42u, (uint32_t)j, (uint32_t)(10 + j), a, bb);
      flat[j] = a; flat[10 + j] = bb;
    }
    for (int j = 0; j < 10; ++j) { ks[j][0] = flat[2 * j]; ks[j][1] = flat[2 * j + 1]; }
  }
#endif
  float* P = prm + b * PSTRIDE;

  float uarea = junif(ks[0][0], ks[0][1], b, NB, 0.8f, 1.0f);
  float area  = __fmul_rn(65536.0f, uarea);
  float lmn = (float)(-0.28768207245178085);
  float lmx = (float)( 0.28768207245178085);
  float ur  = junif(ks[1][0], ks[1][1], b, NB, lmn, lmx);
  float ratio = (float)exp((double)ur);

  float cw = rintf(__fsqrt_rn(__fmul_rn(area, ratio)));
  cw = fminf(fmaxf(cw, 1.0f), 256.0f);
  float ch = rintf(__fsqrt_rn(__fdiv_rn(area, ratio)));
  ch = fminf(fmaxf(ch, 1.0f), 256.0f);

  float ui = u01_n(ks[2][0], ks[2][1], b, NB);
  float uj = u01_n(ks[3][0], ks[3][1], b, NB);
  float i0 = floorf(__fmul_rn(ui, __fadd_rn(__fsub_rn(256.0f, ch), 1.0f)));
  float j0 = floorf(__fmul_rn(uj, __fadd_rn(__fsub_rn(256.0f, cw), 1.0f)));

  float sy = __fdiv_rn(224.0f, ch), sx = __fdiv_rn(224.0f, cw);
  float ty = -__fmul_rn(i0, sy),   tx = -__fmul_rn(j0, sx);
  float inv_sy = __fdiv_rn(1.0f, sy), inv_sx = __fdiv_rn(1.0f, sx);
  P[0] = inv_sy;
  P[1] = __fmul_rn(ty, inv_sy);
  P[2] = fmaxf(inv_sy, 1.0f);
  P[3] = inv_sx;
  P[4] = __fmul_rn(tx, inv_sx);
  P[5] = fmaxf(inv_sx, 1.0f);

  P[6] = junif(ks[4][0], ks[4][1], b, NB, 0.9f, 1.1f);
  P[7] = junif(ks[5][0], ks[5][1], b, NB, 0.9f, 1.1f);
  P[8] = junif(ks[6][0], ks[6][1], b, NB, 0.9f, 1.1f);
  P[9] = junif(ks[7][0], ks[7][1], b, NB, -0.01f, 0.01f);
  P[10] = (u01_n(ks[8][0], ks[8][1], b, NB) < 0.8f) ? 1.0f : 0.0f;

  uint32_t kb0[2], kb1[2];
#if JAX_PARTITIONABLE
  tf2x32(ks[9][0], ks[9][1], 0u, 0u, kb0[0], kb0[1]);
  tf2x32(ks[9][0], ks[9][1], 0u, 1u, kb1[0], kb1[1]);
#else
  {
    uint32_t f0, s0, f1, s1;
    tf2x32(ks[9][0], ks[9][1], 0u, 2u, f0, s0);
    tf2x32(ks[9][0], ks[9][1], 1u, 3u, f1, s1);
    kb0[0] = f0; kb0[1] = f1; kb1[0] = s0; kb1[1] = s1;
  }
#endif
  float sg = junif(kb0[0], kb0[1], b, NB, 0.1f, 2.0f);
  P[11] = (u01_n(kb1[0], kb1[1], b, NB) < 0.5f) ? 1.0f : 0.0f;

  float e[15]; float ssum = 0.0f;
  for (int k = 0; k < 15; ++k) {
    float t = (float)k - 7.0f;
    float z = t / sg;
    e[k] = expf(-0.5f * (z * z));
    ssum += e[k];
  }
  for (int k = 0; k < 15; ++k) P[12 + k] = e[k] / ssum;
}

// ---------------- cubic (Keys, a=-0.5) ----------------
__device__ __forceinline__ float keys_cubic(float x) {
  float o = ((1.5f * x - 2.5f) * x) * x + 1.0f;
  if (x >= 1.0f) o = ((-0.5f * x + 2.5f) * x - 4.0f) * x + 2.0f;
  if (x >= 2.0f) o = 0.0f;
  return o;
}

// ---------------- per-batch resize weight tables ----------------
// wtab[b][dim(0=y,1=x)][o][8]: w0..w5 (zero-padded), i0, ntaps
__global__ __launch_bounds__(224) void k_weights(const float* __restrict__ prm,
                                                 float* __restrict__ wtab) {
  int o = threadIdx.x;
  int dim = blockIdx.x & 1;
  int b = blockIdx.x >> 1;
  const float* P = prm + b * PSTRIDE;
  float inv = dim ? P[3] : P[0];
  float ti  = dim ? P[4] : P[1];
  float ks  = dim ? P[5] : P[2];
  float sf = ((float)o + 0.5f) * inv - ti - 0.5f;
  float r = 2.0f * ks;
  int i0 = max(0, (int)ceilf(sf - r));
  int i1 = min(255, (int)floorf(sf + r));
  int n = i1 - i0 + 1; if (n > 6) n = 6;
  float w[6]; float tot = 0.0f;
  #pragma unroll
  for (int j = 0; j < 6; ++j) {
    float v = 0.0f;
    if (j < n) { float d = fabsf(sf - (float)(i0 + j)) / ks; v = keys_cubic(d); }
    w[j] = v; tot += v;
  }
  float ri = (fabsf(tot) > 1.1920929e-4f) ? (1.0f / tot) : 0.0f;
  float* W = wtab + ((size_t)(b * 2 + dim) * 224 + o) * 8;
  #pragma unroll
  for (int j = 0; j < 6; ++j) W[j] = w[j] * ri;
  W[6] = (float)i0;
  W[7] = (float)n;
}

// ---------------- tiled separable resize (round-7 structure, bf16 out) ----
__global__ __launch_bounds__(256) void k_resize(const float* __restrict__ x,
                                                unsigned short* __restrict__ xcj,
                                                float* __restrict__ rowsum,
                                                const float* __restrict__ prm,
                                                const float* __restrict__ wtab) {
  int blk = blockIdx.x;
  int tile = blk % NTILE;
  int c = (blk / NTILE) % NC;
  int b = blk / (NTILE * NC);
  int t = threadIdx.x;
  int oyb = tile * TROWS;
  const float* P = prm + b * PSTRIDE;
  const float* wty = wtab + ((size_t)(b * 2) * 224 + oyb) * 8;

  __shared__ __align__(16) float s_mem[256 * CSTRIDE];   // 28672 B
  __shared__ __align__(16) float s_wyl[TROWS * 8];       // 512 B y-weight block
  __shared__ float wsum[4];

  if (t < TROWS * 8) s_wyl[t] = wty[t];

  int base = (int)wty[6];

  // stage column t: FIXED 6 chunks of 4 rows (row-clamped), b128 writes
  {
    const float* src = x + (size_t)(b * NC + c) * IH * IW + t;
    float* colp = s_mem + t * CSTRIDE;
    #pragma unroll
    for (int k = 0; k < 6; ++k) {
      float4 v;
      v.x = src[(size_t)min(base + 4 * k + 0, IH - 1) * IW];
      v.y = src[(size_t)min(base + 4 * k + 1, IH - 1) * IW];
      v.z = src[(size_t)min(base + 4 * k + 2, IH - 1) * IW];
      v.w = src[(size_t)min(base + 4 * k + 3, IH - 1) * IW];
      *(float4*)(colp + 4 * k) = v;
    }
  }
  __syncthreads();

  // x-pass into registers: FIXED 6 taps (zero-padded weights are exact)
  float xr[LROWS];
  #pragma unroll
  for (int r = 0; r < LROWS; ++r) xr[r] = 0.0f;
  if (t < OS) {
    const float4* W4 = (const float4*)(wtab + ((size_t)(b * 2 + 1) * 224 + t) * 8);
    float4 wA = W4[0], wB = W4[1];
    int ix0 = (int)wB.z;
    #pragma unroll
    for (int j = 0; j < 6; ++j) {
      float wj = (j == 0) ? wA.x : (j == 1) ? wA.y : (j == 2) ? wA.z
               : (j == 3) ? wA.w : (j == 4) ? wB.x : wB.y;
      const float* colp = s_mem + (ix0 + j) * CSTRIDE;
      #pragma unroll
      for (int k = 0; k < 6; ++k) {
        float4 f = *(const float4*)(colp + 4 * k);
        xr[4 * k + 0] += wj * f.x;
        xr[4 * k + 1] += wj * f.y;
        xr[4 * k + 2] += wj * f.z;
        xr[4 * k + 3] += wj * f.w;
      }
    }
  }
  __syncthreads();

  // writeback col-major stride 25 (conflict-free; merges to ds_write2_b32)
  {
    float* colq = s_mem + t * YSTR;
    #pragma unroll
    for (int r = 0; r < LROWS; ++r) colq[r] = xr[r];
  }
  __syncthreads();

  // y-pass: LDS-broadcast weights, contiguous column reads, bf16 stores
  float bfac = P[6];
  float psum = 0.0f;
  bool act = (t < OS);
  unsigned short* dst = xcj + ((size_t)(b * NC + c) * OS + oyb) * OS + t;
  const float* colq = s_mem + t * YSTR;
  #pragma unroll 2
  for (int i = 0; i < TROWS; ++i) {
    float4 a = *(const float4*)&s_wyl[i * 8];       // w0..w3 (broadcast)
    float4 h = *(const float4*)&s_wyl[i * 8 + 4];   // w4,w5,iy0,n
    int ry0 = (int)h.z - base;
    const float* p = colq + ry0;
    float acc = a.x * p[0] + a.y * p[1] + a.z * p[2]
              + a.w * p[3] + h.x * p[4] + h.y * p[5];
    if (act) {
      dst[(size_t)i * OS] = f2bf(acc);
      psum += fminf(fmaxf(acc * bfac, 0.0f), 1.0f);
    }
  }
  for (int off = 32; off > 0; off >>= 1) psum += __shfl_down(psum, off, 64);
  int wid = t >> 6, lane = t & 63;
  if (lane == 0) wsum[wid] = psum;
  __syncthreads();
  if (t == 0) rowsum[blk] = wsum[0] + wsum[1] + wsum[2] + wsum[3];
}

__global__ __launch_bounds__(64) void k_means(const float* __restrict__ rowsum,
                                              float* __restrict__ means) {
  int b = blockIdx.x, t = threadIdx.x;
  float acc = 0.0f;
  if (t < NC * NTILE) {
    int c = t / NTILE;
    float w = (c == 0) ? 0.2989f : ((c == 1) ? 0.587f : 0.114f);
    acc = w * rowsum[b * NC * NTILE + t];
  }
  for (int off = 32; off > 0; off >>= 1) acc += __shfl_down(acc, off, 64);
  if (t == 0) means[b] = acc / (float)PIX;
}

// ---------------- color jitter ----------------
__device__ __forceinline__ float clip01(float x) { return fminf(fmaxf(x, 0.0f), 1.0f); }
__device__ __forceinline__ float fmod1(float x)  { return x - floorf(x); }

__device__ __forceinline__ void jitter_px(float& r, float& g, float& bb,
                                          float mg, float bfac, float cfac,
                                          float sfac, float hfac) {
  r = clip01(r * bfac); g = clip01(g * bfac); bb = clip01(bb * bfac);
  r  = clip01(cfac * r  + (1.0f - cfac) * mg);
  g  = clip01(cfac * g  + (1.0f - cfac) * mg);
  bb = clip01(cfac * bb + (1.0f - cfac) * mg);
  float gray = 0.2989f * r + 0.587f * g + 0.114f * bb;
  r  = clip01(sfac * r  + (1.0f - sfac) * gray);
  g  = clip01(sfac * g  + (1.0f - sfac) * gray);
  bb = clip01(sfac * bb + (1.0f - sfac) * gray);
  float maxc = fmaxf(r, fmaxf(g, bb));
  float minc = fminf(r, fminf(g, bb));
  float v = maxc, d = maxc - minc;
  float s = (maxc > 0.0f) ? (d / maxc) : 0.0f;
  float dn = (d > 0.0f) ? d : 1.0f;
  float rc = (maxc - r) / dn, gc = (maxc - g) / dn, bc2 = (maxc - bb) / dn;
  float h = (maxc == r) ? (bc2 - gc)
          : ((maxc == g) ? (2.0f + rc - bc2) : (4.0f + gc - rc));
  h = (d > 0.0f) ? fmod1(h / 6.0f) : 0.0f;
  h = fmod1(h + hfac);
  float fi = floorf(h * 6.0f);
  float f = h * 6.0f - fi;
  int i = ((int)fi) % 6;
  float pp = v * (1.0f - s);
  float q  = v * (1.0f - s * f);
  float tt = v * (1.0f - s * (1.0f - f));
  switch (i) {
    case 0: r = v;  g = tt; bb = pp; break;
    case 1: r = q;  g = v;  bb = pp; break;
    case 2: r = pp; g = v;  bb = tt; break;
    case 3: r = pp; g = q;  bb = v;  break;
    case 4: r = tt; g = pp; bb = v;  break;
    default: r = v; g = pp; bb = q;  break;
  }
}

// 4 px/thread from bf16 xcj. Blur batches: jitter in place (bf16); skip write
// if cj==false (bits already correct). Non-blur: write f32 out.
__global__ __launch_bounds__(256) void k_jitter(unsigned short* __restrict__ xcj,
                                                const float* __restrict__ means,
                                                const float* __restrict__ prm,
                                                float* __restrict__ out) {
  int idx = blockIdx.x * 256 + threadIdx.x;
  const int QPB = PIX / 4;
  if (idx >= NB * QPB) return;
  int b = idx / QPB, p4 = idx - b * QPB;
  const float* P = prm + b * PSTRIDE;
  float bfac = P[6], cfac = P[7], sfac = P[8], hfac = P[9];
  bool cj = P[10] != 0.0f;
  bool bl = P[11] != 0.0f;
  if (bl && !cj) return;                     // xj == xc, bits already in place
  size_t base4 = ((size_t)b * NC * PIX) / 4 + p4;
  ushort4* in4 = (ushort4*)xcj;
  ushort4 ru = in4[base4];
  ushort4 gu = in4[base4 + PIX / 4];
  ushort4 bu = in4[base4 + 2 * (PIX / 4)];
  float4 r4 = make_float4(bf2f(ru.x), bf2f(ru.y), bf2f(ru.z), bf2f(ru.w));
  float4 g4 = make_float4(bf2f(gu.x), bf2f(gu.y), bf2f(gu.z), bf2f(gu.w));
  float4 b4 = make_float4(bf2f(bu.x), bf2f(bu.y), bf2f(bu.z), bf2f(bu.w));
  if (cj) {
    float mg = means[b];
    float* rp = (float*)&r4; float* gp = (float*)&g4; float* bp = (float*)&b4;
    #pragma unroll
    for (int k = 0; k < 4; ++k) jitter_px(rp[k], gp[k], bp[k], mg, bfac, cfac, sfac, hfac);
  }
  if (bl) {
    // in-place bf16 write (same addresses this thread read)
    ushort4 s;
    s.x = f2bf(r4.x); s.y = f2bf(r4.y); s.z = f2bf(r4.z); s.w = f2bf(r4.w);
    in4[base4] = s;
    s.x = f2bf(g4.x); s.y = f2bf(g4.y); s.z = f2bf(g4.z); s.w = f2bf(g4.w);
    in4[base4 + PIX / 4] = s;
    s.x = f2bf(b4.x); s.y = f2bf(b4.y); s.z = f2bf(b4.z); s.w = f2bf(b4.w);
    in4[base4 + 2 * (PIX / 4)] = s;
  } else {
    float4* dst4 = (float4*)out;
    dst4[base4] = r4;
    dst4[base4 + PIX / 4] = g4;
    dst4[base4 + 2 * (PIX / 4)] = b4;
  }
}

// ---------------- separable gaussian blur (reflect), gated per b ----------
// staging: raw bf16 halo copy; y-pass: contribution trick into acc[16]
// (bit-identical k-ascending order); x-pass from f32 mid with reg weights.
__global__ __launch_bounds__(256) void k_blur(const unsigned short* __restrict__ xcj,
                                              float* __restrict__ out,
                                              const float* __restrict__ prm) {
  int blk = blockIdx.x;
  int tile = blk % NTILE;
  int c = (blk / NTILE) % NC;
  int b = blk / (NTILE * NC);
  const float* P = prm + b * PSTRIDE;
  if (P[11] == 0.0f) return;
  int t = threadIdx.x;
  int oyb = tile * TROWS;

  __shared__ unsigned short s_in[TROWS + 14][228];   // 13,680 B (bf16 halo)
  __shared__ float s_mid[TROWS][226];                // 14,464 B
  __shared__ float s_k[15];
  if (t < 15) s_k[t] = P[12 + t];

  const unsigned short* plane = xcj + (size_t)(b * NC + c) * PIX;
  float* oplane = out + (size_t)(b * NC + c) * PIX;

  // stage 30 reflected rows as raw bf16 (ushort4 copies)
  {
    const int RQ = OS / 4;                           // 56 quads per row
    for (int f = t; f < (TROWS + 14) * RQ; f += 256) {
      int r = f / RQ, q = f - r * RQ;
      int yy = oyb - 7 + r;
      yy = (yy < 0) ? -yy : ((yy > OS - 1) ? (2 * (OS - 1) - yy) : yy);
      *(ushort4*)&s_in[r][4 * q] = *(const ushort4*)(plane + (size_t)yy * OS + 4 * q);
    }
  }
  __syncthreads();

  // weights to registers (broadcast reads, once)
  float w[15];
  #pragma unroll
  for (int k = 0; k < 15; ++k) w[k] = s_k[k];

  // y-pass: contribution trick — 30 reads, 240 static fmacs, exact FP order
  float acc[TROWS];
  #pragma unroll
  for (int i = 0; i < TROWS; ++i) acc[i] = 0.0f;
  if (t < OS) {
    #pragma unroll
    for (int r = 0; r < TROWS + 14; ++r) {
      float val = bf2f(s_in[r][t]);
      #pragma unroll
      for (int i = 0; i < TROWS; ++i) {
        if (i <= r && r - i <= 14) acc[i] += w[r - i] * val;
      }
    }
    #pragma unroll
    for (int i = 0; i < TROWS; ++i) s_mid[i][t] = acc[i];
  }
  __syncthreads();

  // x-pass with reflect, weights from registers
  if (t < OS) {
    for (int i = 0; i < TROWS; ++i) {
      float a2 = 0.0f;
      #pragma unroll
      for (int k = 0; k < 15; ++k) {
        int xx = t - 7 + k;
        xx = (xx < 0) ? -xx : ((xx > OS - 1) ? (2 * (OS - 1) - xx) : xx);
        a2 += w[k] * s_mid[i][xx];
      }
      oplane[(size_t)(oyb + i) * OS + t] = a2;
    }
  }
}

// ---------------- launch ----------------
extern "C" void kernel_launch(void* const* d_in, const int* in_sizes, int n_in,
                              void* d_out, int out_size, void* d_ws, size_t ws_size,
                              hipStream_t stream) {
  const float* x = (const float*)d_in[0];
  float* out = (float*)d_out;
  char* ws = (char*)d_ws;

  float* prm    = (float*)ws;                            // 32768 B
  float* rowsum = (float*)(ws + 32768);                  // 43008 B
  float* means  = (float*)(ws + 75776);                  // 1024 B
  float* wtab   = (float*)(ws + 76800);                  // 3670016 B
  unsigned short* xcj = (unsigned short*)(ws + 3746816); // 77070336 B (bf16 xc/xj)

  k_params<<<1, 256, 0, stream>>>(prm);
  k_weights<<<NB * 2, 224, 0, stream>>>(prm, wtab);

  int nblk = NB * NC * NTILE;                            // 10752
  k_resize<<<nblk, 256, 0, stream>>>(x, xcj, rowsum, prm, wtab);  // xc -> xcj
  k_means<<<NB, 64, 0, stream>>>(rowsum, means);

  int nquad = NB * (PIX / 4);                            // 3211264
  k_jitter<<<(nquad + 255) / 256, 256, 0, stream>>>(xcj, means, prm, out);

  k_blur<<<nblk, 256, 0, stream>>>(xcj, out, prm);       // blurred b: xcj -> out
}